// Round 2
// baseline (2582.702 us; speedup 1.0000x reference)
//
#include <hip/hip_runtime.h>
#include <math.h>

#define N_TOTAL    262144
#define NUM_SAMPLE 1024
#define FPS_BLOCKS 64
#define FPS_THREADS 256
#define FPS_PPT (N_TOTAL / (FPS_BLOCKS * FPS_THREADS))   // 16
#define M_WAVE 16                                         // published cands per wave
#define POOL (FPS_BLOCKS * 4 * M_WAVE)                    // 4096
#define ENT_PER_T (POOL / FPS_THREADS)                    // 16
#define ACT_PER_T 4                                       // actives per thread
#define ACT (FPS_THREADS * ACT_PER_T)                     // 1024 (16 per wave0-lane)
#define QD (ACT / 64)                                     // 16 register actives/lane
#define SEL_CAP 1023

__device__ __forceinline__ float addrn(float a, float b) { return __fadd_rn(a, b); }
__device__ __forceinline__ float subrn(float a, float b) { return __fsub_rn(a, b); }
__device__ __forceinline__ float mulrn(float a, float b) { return __fmul_rn(a, b); }

__device__ __forceinline__ float d2rn(float ax, float ay, float az,
                                      float bx, float by, float bz) {
  float dx = subrn(ax, bx), dy = subrn(ay, by), dz = subrn(az, bz);
  return addrn(addrn(mulrn(dx, dx), mulrn(dy, dy)), mulrn(dz, dz));
}

__device__ __forceinline__ bool lex_gt(float m1, unsigned i1, float m2, unsigned i2) {
  return (m1 > m2) || (m1 == m2 && i1 > i2);
}
__device__ __forceinline__ bool lex_ge(float m1, unsigned i1, float m2, unsigned i2) {
  return (m1 > m2) || (m1 == m2 && i1 >= i2);
}

// ---- DPP wave64 max-reduce + SGPR broadcast (no LDS pipe, pure VALU) ----
template <int CTRL>
__device__ __forceinline__ int dpp_i(int x) {
  return __builtin_amdgcn_update_dpp(x, x, CTRL, 0xF, 0xF, false);
}
__device__ __forceinline__ float wave_fmax_bcast(float v) {
  v = fmaxf(v, __int_as_float(dpp_i<0x111>(__float_as_int(v))));   // row_shr:1
  v = fmaxf(v, __int_as_float(dpp_i<0x112>(__float_as_int(v))));   // row_shr:2
  v = fmaxf(v, __int_as_float(dpp_i<0x114>(__float_as_int(v))));   // row_shr:4
  v = fmaxf(v, __int_as_float(dpp_i<0x118>(__float_as_int(v))));   // row_shr:8
  v = fmaxf(v, __int_as_float(dpp_i<0x142>(__float_as_int(v))));   // row_bcast:15
  v = fmaxf(v, __int_as_float(dpp_i<0x143>(__float_as_int(v))));   // row_bcast:31
  return __int_as_float(__builtin_amdgcn_readlane(__float_as_int(v), 63));
}
__device__ __forceinline__ unsigned wave_umax_bcast(unsigned v) {
  unsigned o;
  o = (unsigned)dpp_i<0x111>((int)v); v = (o > v) ? o : v;
  o = (unsigned)dpp_i<0x112>((int)v); v = (o > v) ? o : v;
  o = (unsigned)dpp_i<0x114>((int)v); v = (o > v) ? o : v;
  o = (unsigned)dpp_i<0x118>((int)v); v = (o > v) ? o : v;
  o = (unsigned)dpp_i<0x142>((int)v); v = (o > v) ? o : v;
  o = (unsigned)dpp_i<0x143>((int)v); v = (o > v) ? o : v;
  return (unsigned)__builtin_amdgcn_readlane((int)v, 63);
}

// ---------------- LAPACK emulation (f32) ----------------
__device__ __forceinline__ float slapy2f(float x, float y) {
  float xa = fabsf(x), ya = fabsf(y);
  float w = fmaxf(xa, ya), z = fminf(xa, ya);
  if (z == 0.f) return w;
  float t = z / w;
  return w * __fsqrt_rn(1.f + t * t);
}

__device__ __forceinline__ void slartgf(float f, float g, float& c, float& s, float& r) {
  if (g == 0.f) { c = 1.f; s = 0.f; r = f; }
  else if (f == 0.f) { c = 0.f; s = (g > 0.f) ? 1.f : -1.f; r = fabsf(g); }
  else {
    float d = __fsqrt_rn(f * f + g * g);
    c = fabsf(f) / d;
    r = (f >= 0.f) ? d : -d;
    s = g / r;
  }
}

__device__ void slaev2f(float a, float b, float c0, float& rt1, float& rt2,
                        float& cs1, float& sn1) {
  float sm = a + c0, df = a - c0;
  float adf = fabsf(df), tb = b + b, ab = fabsf(tb);
  float acmx, acmn;
  if (fabsf(a) > fabsf(c0)) { acmx = a; acmn = c0; } else { acmx = c0; acmn = a; }
  float rt;
  if (adf > ab)      { float t = ab / adf; rt = adf * __fsqrt_rn(1.f + t * t); }
  else if (adf < ab) { float t = adf / ab; rt = ab * __fsqrt_rn(1.f + t * t); }
  else               { rt = ab * __fsqrt_rn(2.f); }
  int sgn1;
  if (sm < 0.f)      { rt1 = 0.5f * (sm - rt); sgn1 = -1; rt2 = (acmx / rt1) * acmn - (b / rt1) * b; }
  else if (sm > 0.f) { rt1 = 0.5f * (sm + rt); sgn1 = 1;  rt2 = (acmx / rt1) * acmn - (b / rt1) * b; }
  else               { rt1 = 0.5f * rt; rt2 = -0.5f * rt; sgn1 = 1; }
  float cs; int sgn2;
  if (df >= 0.f) { cs = df + rt; sgn2 = 1; } else { cs = df - rt; sgn2 = -1; }
  float acs = fabsf(cs);
  if (acs > ab) {
    float ct = -tb / cs;
    sn1 = 1.f / __fsqrt_rn(1.f + ct * ct);
    cs1 = ct * sn1;
  } else {
    if (ab == 0.f) { cs1 = 1.f; sn1 = 0.f; }
    else { float tn = -cs / tb; cs1 = 1.f / __fsqrt_rn(1.f + tn * tn); sn1 = tn * cs1; }
  }
  if (sgn1 == sgn2) { float tn = cs1; cs1 = -sn1; sn1 = tn; }
}

#define D_(i) d[(i)-1]
#define E_(i) e[(i)-1]

__device__ void ssteqr3(float d[3], float e[2], float Z[3][3]) {
  const float eps    = 5.9604645e-08f;
  const float eps2   = 3.5527137e-15f;
  const float safmin = 1.17549435e-38f;
  const float ssfmax = 3.0744573e+18f;
  const float ssfmin = 3.0517578e-05f;
  const int n = 3;
  int jtot = 0, nmaxit = 90;
  int l1 = 1;

  while (true) {
    if (l1 > n) break;
    if (l1 > 1) E_(l1 - 1) = 0.f;
    int m = n;
    for (int mm = l1; mm <= n - 1; ++mm) {
      float tst = fabsf(E_(mm));
      if (tst == 0.f) { m = mm; break; }
      if (tst <= (__fsqrt_rn(fabsf(D_(mm))) * __fsqrt_rn(fabsf(D_(mm + 1)))) * eps) {
        E_(mm) = 0.f; m = mm; break;
      }
    }
    int l = l1, lsv = l, lend = m, lendsv = m;
    l1 = m + 1;
    if (lend == l) continue;

    float anorm = fabsf(D_(lend));
    for (int i2 = l; i2 <= lend - 1; ++i2) {
      anorm = fmaxf(anorm, fabsf(D_(i2)));
      anorm = fmaxf(anorm, fabsf(E_(i2)));
    }
    int iscale = 0;
    if (anorm == 0.f) continue;
    if (anorm > ssfmax) {
      iscale = 1; float mul = ssfmax / anorm;
      for (int i2 = l; i2 <= lend; ++i2) D_(i2) *= mul;
      for (int i2 = l; i2 <= lend - 1; ++i2) E_(i2) *= mul;
    } else if (anorm < ssfmin) {
      iscale = 2; float mul = ssfmin / anorm;
      for (int i2 = l; i2 <= lend; ++i2) D_(i2) *= mul;
      for (int i2 = l; i2 <= lend - 1; ++i2) E_(i2) *= mul;
    }

    if (fabsf(D_(lend)) < fabsf(D_(l))) { int t = l; l = lend; lend = t; }

    if (lend > l) {
      while (true) {
        int m2 = lend;
        if (l != lend) {
          for (int mm = l; mm <= lend - 1; ++mm) {
            float tst = fabsf(E_(mm)); tst = tst * tst;
            if (tst <= (eps2 * fabsf(D_(mm))) * fabsf(D_(mm + 1)) + safmin) { m2 = mm; break; }
          }
        }
        if (m2 < lend) E_(m2) = 0.f;
        float p = D_(l);
        if (m2 == l) { D_(l) = p; l = l + 1; if (l <= lend) continue; break; }
        if (m2 == l + 1) {
          float rt1, rt2, cc, ss;
          slaev2f(D_(l), E_(l), D_(l + 1), rt1, rt2, cc, ss);
          for (int i2 = 0; i2 < 3; ++i2) {
            float tmp = Z[i2][l];
            Z[i2][l]     = cc * tmp - ss * Z[i2][l - 1];
            Z[i2][l - 1] = ss * tmp + cc * Z[i2][l - 1];
          }
          D_(l) = rt1; D_(l + 1) = rt2; E_(l) = 0.f;
          l = l + 2; if (l <= lend) continue; break;
        }
        if (jtot == nmaxit) break;
        ++jtot;
        float g = (D_(l + 1) - p) / (2.f * E_(l));
        float r = slapy2f(g, 1.f);
        float sgn_rg = (g >= 0.f) ? r : -r;
        g = D_(m2) - p + E_(l) / (g + sgn_rg);
        float s = 1.f, c = 1.f;
        p = 0.f;
        float csv[2], ssv[2];
        for (int i2 = m2 - 1; i2 >= l; --i2) {
          float f = s * E_(i2);
          float b = c * E_(i2);
          slartgf(g, f, c, s, r);
          if (i2 != m2 - 1) E_(i2 + 1) = r;
          g = D_(i2 + 1) - p;
          r = (D_(i2) - g) * s + 2.f * c * b;
          p = s * r;
          D_(i2 + 1) = g + p;
          g = c * r - b;
          csv[i2 - l] = c; ssv[i2 - l] = -s;
        }
        for (int j = m2 - 1; j >= l; --j) {
          float ct = csv[j - l], st = ssv[j - l];
          for (int i2 = 0; i2 < 3; ++i2) {
            float tmp = Z[i2][j];
            Z[i2][j]     = ct * tmp - st * Z[i2][j - 1];
            Z[i2][j - 1] = st * tmp + ct * Z[i2][j - 1];
          }
        }
        D_(l) = D_(l) - p;
        E_(l) = g;
      }
    } else {
      while (true) {
        int m2 = lend;
        if (l != lend) {
          for (int mm = l; mm >= lend + 1; --mm) {
            float tst = fabsf(E_(mm - 1)); tst = tst * tst;
            if (tst <= (eps2 * fabsf(D_(mm))) * fabsf(D_(mm - 1)) + safmin) { m2 = mm; break; }
          }
        }
        if (m2 > lend) E_(m2 - 1) = 0.f;
        float p = D_(l);
        if (m2 == l) { D_(l) = p; l = l - 1; if (l >= lend) continue; break; }
        if (m2 == l - 1) {
          float rt1, rt2, cc, ss;
          slaev2f(D_(l - 1), E_(l - 1), D_(l), rt1, rt2, cc, ss);
          for (int i2 = 0; i2 < 3; ++i2) {
            float tmp = Z[i2][l - 1];
            Z[i2][l - 1] = cc * tmp - ss * Z[i2][l - 2];
            Z[i2][l - 2] = ss * tmp + cc * Z[i2][l - 2];
          }
          D_(l - 1) = rt1; D_(l) = rt2; E_(l - 1) = 0.f;
          l = l - 2; if (l >= lend) continue; break;
        }
        if (jtot == nmaxit) break;
        ++jtot;
        float g = (D_(l - 1) - p) / (2.f * E_(l - 1));
        float r = slapy2f(g, 1.f);
        float sgn_rg = (g >= 0.f) ? r : -r;
        g = D_(m2) - p + E_(l - 1) / (g + sgn_rg);
        float s = 1.f, c = 1.f;
        p = 0.f;
        float csv[2], ssv[2];
        for (int i2 = m2; i2 <= l - 1; ++i2) {
          float f = s * E_(i2);
          float b = c * E_(i2);
          slartgf(g, f, c, s, r);
          if (i2 != m2) E_(i2 - 1) = r;
          g = D_(i2) - p;
          r = (D_(i2 + 1) - g) * s + 2.f * c * b;
          p = s * r;
          D_(i2) = g + p;
          g = c * r - b;
          csv[i2 - m2] = c; ssv[i2 - m2] = s;
        }
        for (int j = m2; j <= l - 1; ++j) {
          float ct = csv[j - m2], st = ssv[j - m2];
          for (int i2 = 0; i2 < 3; ++i2) {
            float tmp = Z[i2][j];
            Z[i2][j]     = ct * tmp - st * Z[i2][j - 1];
            Z[i2][j - 1] = st * tmp + ct * Z[i2][j - 1];
          }
        }
        D_(l) = D_(l) - p;
        E_(l - 1) = g;
      }
    }
    if (iscale == 1) {
      float mul = anorm / ssfmax;
      for (int i2 = lsv; i2 <= lendsv; ++i2) D_(i2) *= mul;
      for (int i2 = lsv; i2 <= lendsv - 1; ++i2) E_(i2) *= mul;
    } else if (iscale == 2) {
      float mul = anorm / ssfmin;
      for (int i2 = lsv; i2 <= lendsv; ++i2) D_(i2) *= mul;
      for (int i2 = lsv; i2 <= lendsv - 1; ++i2) E_(i2) *= mul;
    }
  }
  for (int ii = 2; ii <= n; ++ii) {
    int i2 = ii - 1, k = i2;
    float p = D_(i2);
    for (int j = ii; j <= n; ++j) if (D_(j) < p) { k = j; p = D_(j); }
    if (k != i2) {
      D_(k) = D_(i2); D_(i2) = p;
      for (int rr = 0; rr < 3; ++rr) {
        float t = Z[rr][i2 - 1]; Z[rr][i2 - 1] = Z[rr][k - 1]; Z[rr][k - 1] = t;
      }
    }
  }
}

__device__ void eigh3_smallest(float a00, float a10, float a20, float a11, float a21, float a22,
                               float& nx, float& ny, float& nz) {
  float d[3], e[2];
  float Z[3][3] = {{1.f,0.f,0.f},{0.f,1.f,0.f},{0.f,0.f,1.f}};
  float tau, v2;
  {
    float alpha = a10, x = a20;
    float xnorm = fabsf(x);
    if (xnorm == 0.f) {
      tau = 0.f; v2 = 0.f;
      d[0] = a00; d[1] = a11; d[2] = a22;
      e[0] = alpha; e[1] = a21;
    } else {
      float beta = -copysignf(slapy2f(alpha, x), alpha);
      tau = (beta - alpha) / beta;
      v2 = x / (alpha - beta);
      float w0 = (tau * a11) + tau * (a21 * v2);
      float w1 = (tau * a21) + (tau * v2) * a22;
      float ac = (-0.5f * tau) * (w0 + w1 * v2);
      w0 = w0 + ac;
      w1 = w1 + ac * v2;
      d[0] = a00;
      d[1] = (a11 - w0) - w0;
      d[2] = (a22 - v2 * w1) - w1 * v2;
      e[0] = beta;
      e[1] = (a21 - v2 * w0) - w1;
    }
  }
  ssteqr3(d, e, Z);
  if (tau != 0.f) {
    for (int c = 0; c < 3; ++c) {
      float w = Z[1][c] + Z[2][c] * v2;
      float temp = (-tau) * w;
      Z[1][c] = Z[1][c] + temp;
      Z[2][c] = Z[2][c] + v2 * temp;
    }
  }
  nx = Z[0][0]; ny = Z[1][0]; nz = Z[2][0];
}

// ---------------- K0: init workspace ----------------
__global__ void k0_init(unsigned long long* cand, int* sample_idx) {
  int t = blockIdx.x * blockDim.x + threadIdx.x;
  if (t < 2 * POOL) cand[t] = 0ull;
  if (t == 0) sample_idx[0] = 0;
}

// ---------------- K1: batched FPS ----------------
// Round-1 post-mortem: the per-batch FIXED costs dominate (69 us/batch x 22
// batches), not the per-pick chain. This version amortizes them:
//  - M_WAVE 8->16: batch bound Tmd = max of 16th-bests (pool rank ~1230 vs
//    ~482) -> ~2x picks/batch -> ~10-12 batches (halves publish/poll/skew).
//  - actives 2->4 per thread (1024, 16/lane in wave0 regs): refill bound T2 =
//    max of 5th-bests (rank ~220 vs ~73) -> ~3x longer pick-runs -> ~1-3
//    refills/batch instead of ~8 (each refill = 2 barriers + rescan).
//  - sel stored as float4 + 1-deep pipeline: 1 ds_read_b128/pick in Phase A
//    and refill catch-up, latency hidden under the 16-point update math.
// Exactness invariants unchanged: published words per wave are lex-descending;
// any unpublished point <= its wave's word15 <= Tmd; any non-active pool entry
// <= its thread's 5th-best <= T2; values only decay; while winner >= T2 the
// active max IS the exact global argmax; ties broken by idf (smaller original
// index wins) exactly as the reference's first-max argmax.
__global__ __launch_bounds__(FPS_THREADS, 1) void k1_fps(
    const float* __restrict__ pos,
    unsigned long long* __restrict__ cand,
    int* __restrict__ sample_idx) {
  __shared__ float4 sel4[SEL_CAP];
  __shared__ float act_md[ACT], act_x[ACT], act_y[ACT], act_z[ACT];
  __shared__ unsigned act_idf[ACT];
  __shared__ float thr5_md[FPS_THREADS];      // per-thread 5th-best (T2 source)
  __shared__ unsigned thr5_idf[FPS_THREADS];
  __shared__ float thrT_md[FPS_THREADS];      // per-thread 16th-best (Tmd source)
  __shared__ unsigned thrT_idf[FPS_THREADS];
  __shared__ int sh_flag, sh_pc;

  const int tidx = threadIdx.x;
  const int lane = tidx & 63;
  const int gtid = blockIdx.x * FPS_THREADS + tidx;

  float px[FPS_PPT], py[FPS_PPT], pz[FPS_PPT], md[FPS_PPT];
#pragma unroll
  for (int k = 0; k < FPS_PPT; ++k) {
    int p = gtid + k * (FPS_BLOCKS * FPS_THREADS);
    px[k] = pos[3 * p]; py[k] = pos[3 * p + 1]; pz[k] = pos[3 * p + 2];
    md[k] = 1e10f;
  }
  const unsigned idf0 = 0x3FFFFFu - (unsigned)gtid;
  if (tidx == 0) sel4[0] = make_float4(pos[0], pos[1], pos[2], 0.f);
  __syncthreads();
  int sel_cnt = 1, total = 0, bt = 0;
  while (total < NUM_SAMPLE - 1) {
    ++bt;
    // ---- Phase A: owner md updates vs previous batch's picks (pipelined) ----
    {
      float4 sc = sel4[0];
      for (int s = 0; s < sel_cnt; ++s) {
        float4 sn = (s + 1 < sel_cnt) ? sel4[s + 1] : sc;
#pragma unroll
        for (int k = 0; k < FPS_PPT; ++k)
          md[k] = fminf(md[k], d2rn(px[k], py[k], pz[k], sc.x, sc.y, sc.z));
        sc = sn;
      }
    }
    // ---- per-wave top-16 via DPP (registers only, barrier-free) ----
    const unsigned tag = (unsigned)bt & 1023u;
    unsigned long long* setbase = cand + (size_t)(bt & 1) * POOL;
    {
      const int wv = tidx >> 6;
      float wmd[FPS_PPT];
#pragma unroll
      for (int k = 0; k < FPS_PPT; ++k) wmd[k] = md[k];
      unsigned long long mypub = 0ull;
      for (int r = 0; r < M_WAVE; ++r) {
        float bm = wmd[0]; unsigned bidf = idf0;
#pragma unroll
        for (int k = 1; k < FPS_PPT; ++k) {
          unsigned idfk = idf0 - ((unsigned)k << 14);
          if (wmd[k] > bm || (wmd[k] == bm && idfk > bidf)) { bm = wmd[k]; bidf = idfk; }
        }
        float wmx = wave_fmax_bcast(bm);
        unsigned tb = (bm == wmx) ? bidf : 0u;
        unsigned widf = wave_umax_bcast(tb);
        if (lane == r)
          mypub = ((unsigned long long)__float_as_uint(wmx) << 32) |
                  ((unsigned long long)widf << 10);
#pragma unroll
        for (int k = 0; k < FPS_PPT; ++k) {
          unsigned idfk = idf0 - ((unsigned)k << 14);
          if (wmd[k] == wmx && idfk == widf) wmd[k] = -1.f;
        }
      }
      if (lane < M_WAVE)
        __hip_atomic_store(setbase + blockIdx.x * (4 * M_WAVE) + wv * M_WAVE + lane,
                           mypub | tag, __ATOMIC_RELAXED, __HIP_MEMORY_SCOPE_AGENT);
    }
    // ---- Phase B: poll own 16 words; gather xyz inline as tags arrive ----
    const int base_w = tidx * ENT_PER_T;
    float cmd[ENT_PER_T]; unsigned cidf[ENT_PER_T];
    float cx[ENT_PER_T], cy[ENT_PER_T], cz[ENT_PER_T];
    {
      unsigned done = 0;
      while (done != 0xFFFFu) {
#pragma unroll
        for (int j = 0; j < ENT_PER_T; ++j) {
          if (!((done >> j) & 1u)) {
            unsigned long long v = __hip_atomic_load(setbase + base_w + j,
                                                     __ATOMIC_RELAXED, __HIP_MEMORY_SCOPE_AGENT);
            if ((unsigned)(v & 1023ull) == tag) {
              done |= 1u << j;
              cmd[j] = __uint_as_float((unsigned)(v >> 32));
              cidf[j] = (unsigned)((v >> 10) & 0x3FFFFFull);
              int gidx = 0x3FFFFF - (int)cidf[j];
              cx[j] = pos[3 * gidx]; cy[j] = pos[3 * gidx + 1]; cz[j] = pos[3 * gidx + 2];
            }
          }
        }
        if (done != 0xFFFFu) __builtin_amdgcn_s_sleep(1);
      }
    }
    // ---- initial actives (per-thread top-4 = words 0..3) + bound sources ----
    {
      int e = ACT_PER_T * tidx;
#pragma unroll
      for (int k = 0; k < ACT_PER_T; ++k) {
        act_md[e + k] = cmd[k]; act_idf[e + k] = cidf[k];
        act_x[e + k] = cx[k]; act_y[e + k] = cy[k]; act_z[e + k] = cz[k];
      }
      thr5_md[tidx] = cmd[ACT_PER_T]; thr5_idf[tidx] = cidf[ACT_PER_T];
      thrT_md[tidx] = cmd[ENT_PER_T - 1]; thrT_idf[tidx] = cidf[ENT_PER_T - 1];
    }
    __syncthreads();
    const int room = (NUM_SAMPLE - 1) - total;
    // wave0's register-resident actives (16 entries per lane) + bounds
    float q_md[QD], q_x[QD], q_y[QD], q_z[QD];
    unsigned q_idf[QD];
    float Tmd = 0.f, T2m = 0.f;
    unsigned Tidf = 0u, T2i = 0u;
    if (tidx < 64) {
#pragma unroll
      for (int r = 0; r < QD; ++r) {
        int e2 = lane + 64 * r;
        q_md[r] = act_md[e2]; q_idf[r] = act_idf[e2];
        q_x[r] = act_x[e2]; q_y[r] = act_y[e2]; q_z[r] = act_z[e2];
      }
      // Tmd = lex-max over 256 threads of their 16th-best
      float rm = thrT_md[lane]; unsigned ri = thrT_idf[lane];
#pragma unroll
      for (int r = 1; r < 4; ++r) {
        float m = thrT_md[lane + 64 * r]; unsigned ii = thrT_idf[lane + 64 * r];
        if (lex_gt(m, ii, rm, ri)) { rm = m; ri = ii; }
      }
      Tmd = wave_fmax_bcast(rm);
      unsigned tbT = (rm == Tmd) ? ri : 0u;
      Tidf = wave_umax_bcast(tbT);
      // T2 = lex-max over 256 threads of their 5th-best
      float rm2 = thr5_md[lane]; unsigned ri2 = thr5_idf[lane];
#pragma unroll
      for (int r = 1; r < 4; ++r) {
        float m = thr5_md[lane + 64 * r]; unsigned ii = thr5_idf[lane + 64 * r];
        if (lex_gt(m, ii, rm2, ri2)) { rm2 = m; ri2 = ii; }
      }
      T2m = wave_fmax_bcast(rm2);
      unsigned tb2 = (rm2 == T2m) ? ri2 : 0u;
      T2i = wave_umax_bcast(tb2);
    }
    int picks = 0, myq = 0, pc = 0;
    for (;;) {  // event loop: pick-run in wave0, refill by all, end by flag
      if (tidx < 64) {
        int ev = 0;
        for (;;) {  // pick-run: no barrier, no LDS round-trip
          float bm = q_md[0]; unsigned bidf = q_idf[0];
          float bx = q_x[0], by = q_y[0], bz = q_z[0];
#pragma unroll
          for (int j = 1; j < QD; ++j) {
            bool g = (q_md[j] > bm) || (q_md[j] == bm && q_idf[j] > bidf);
            if (g) { bm = q_md[j]; bidf = q_idf[j]; bx = q_x[j]; by = q_y[j]; bz = q_z[j]; }
          }
          float wmx = wave_fmax_bcast(bm);
          unsigned long long ball = __ballot(bm == wmx);
          unsigned widf; int owner;
          if (__builtin_popcountll(ball) == 1) {
            owner = __builtin_ctzll(ball);
            widf = (unsigned)__builtin_amdgcn_readlane((int)bidf, owner);
          } else {  // md tie across lanes: rare exact-tiebreak path
            unsigned tb = (bm == wmx) ? bidf : 0u;
            widf = wave_umax_bcast(tb);
            owner = __builtin_ctzll(__ballot(bm == wmx && bidf == widf));
          }
          if (picks >= room) { ev = 0; break; }
          if (!lex_ge(wmx, widf, T2m, T2i)) { ev = 1; break; }   // need refill
          if (!lex_ge(wmx, widf, Tmd, Tidf)) { ev = 0; break; }  // batch done
          float X = __int_as_float(__builtin_amdgcn_readlane(__float_as_int(bx), owner));
          float Y = __int_as_float(__builtin_amdgcn_readlane(__float_as_int(by), owner));
          float Z = __int_as_float(__builtin_amdgcn_readlane(__float_as_int(bz), owner));
          if (lane == 0) {
            sel4[picks] = make_float4(X, Y, Z, 0.f);
            if (blockIdx.x == 0) sample_idx[1 + total + picks] = 0x3FFFFF - (int)widf;
          }
#pragma unroll
          for (int j = 0; j < QD; ++j)  // winner self-kills: d2(p,p)=0 exactly
            q_md[j] = fminf(q_md[j], d2rn(q_x[j], q_y[j], q_z[j], X, Y, Z));
          ++picks;
        }
        if (lane == 0) { sh_flag = ev; sh_pc = picks; }
      }
      __syncthreads();
      int ev = sh_flag; pc = sh_pc;
      if (ev == 0) break;
      // ---- refill: bring pool entries up to date vs picks since last sync ----
      if (myq < pc) {
        float4 sc = sel4[myq];
        for (int q = myq; q < pc; ++q) {
          float4 sn = (q + 1 < pc) ? sel4[q + 1] : sc;
#pragma unroll
          for (int j = 0; j < ENT_PER_T; ++j)
            cmd[j] = fminf(cmd[j], d2rn(cx[j], cy[j], cz[j], sc.x, sc.y, sc.z));
          sc = sn;
        }
        myq = pc;
      }
      // per-thread top-5 (lex) of its 16 current pool entries; coords for 1..4
      {
        float m1 = -1.f, m2 = -1.f, m3 = -1.f, m4 = -1.f, m5 = -1.f;
        unsigned i1 = 0u, i2v = 0u, i3v = 0u, i4v = 0u, i5v = 0u;
        float x1 = 0.f, y1 = 0.f, z1 = 0.f, x2 = 0.f, y2 = 0.f, z2 = 0.f;
        float x3 = 0.f, y3 = 0.f, z3 = 0.f, x4 = 0.f, y4 = 0.f, z4 = 0.f;
#pragma unroll
        for (int j = 0; j < ENT_PER_T; ++j) {
          float m = cmd[j]; unsigned ii = cidf[j];
          float xx = cx[j], yy = cy[j], zz = cz[j];
          bool g1 = lex_gt(m, ii, m1, i1);
          bool g2 = lex_gt(m, ii, m2, i2v);
          bool g3 = lex_gt(m, ii, m3, i3v);
          bool g4 = lex_gt(m, ii, m4, i4v);
          bool g5 = lex_gt(m, ii, m5, i5v);
          m5 = g4 ? m4 : (g5 ? m : m5); i5v = g4 ? i4v : (g5 ? ii : i5v);
          m4 = g3 ? m3 : (g4 ? m : m4); i4v = g3 ? i3v : (g4 ? ii : i4v);
          x4 = g3 ? x3 : (g4 ? xx : x4); y4 = g3 ? y3 : (g4 ? yy : y4); z4 = g3 ? z3 : (g4 ? zz : z4);
          m3 = g2 ? m2 : (g3 ? m : m3); i3v = g2 ? i2v : (g3 ? ii : i3v);
          x3 = g2 ? x2 : (g3 ? xx : x3); y3 = g2 ? y2 : (g3 ? yy : y3); z3 = g2 ? z2 : (g3 ? zz : z3);
          m2 = g1 ? m1 : (g2 ? m : m2); i2v = g1 ? i1 : (g2 ? ii : i2v);
          x2 = g1 ? x1 : (g2 ? xx : x2); y2 = g1 ? y1 : (g2 ? yy : y2); z2 = g1 ? z1 : (g2 ? zz : z2);
          m1 = g1 ? m : m1; i1 = g1 ? ii : i1;
          x1 = g1 ? xx : x1; y1 = g1 ? yy : y1; z1 = g1 ? zz : z1;
        }
        int e = ACT_PER_T * tidx;
        act_md[e]     = m1; act_idf[e]     = i1;  act_x[e]     = x1; act_y[e]     = y1; act_z[e]     = z1;
        act_md[e + 1] = m2; act_idf[e + 1] = i2v; act_x[e + 1] = x2; act_y[e + 1] = y2; act_z[e + 1] = z2;
        act_md[e + 2] = m3; act_idf[e + 2] = i3v; act_x[e + 2] = x3; act_y[e + 2] = y3; act_z[e + 2] = z3;
        act_md[e + 3] = m4; act_idf[e + 3] = i4v; act_x[e + 3] = x4; act_y[e + 3] = y4; act_z[e + 3] = z4;
        thr5_md[tidx] = m5; thr5_idf[tidx] = i5v;
      }
      __syncthreads();
      if (tidx < 64) {
#pragma unroll
        for (int r = 0; r < QD; ++r) {
          int e2 = lane + 64 * r;
          q_md[r] = act_md[e2]; q_idf[r] = act_idf[e2];
          q_x[r] = act_x[e2]; q_y[r] = act_y[e2]; q_z[r] = act_z[e2];
        }
        float rm = thr5_md[lane]; unsigned ri = thr5_idf[lane];
#pragma unroll
        for (int r = 1; r < 4; ++r) {
          float m = thr5_md[lane + 64 * r]; unsigned ii = thr5_idf[lane + 64 * r];
          if (lex_gt(m, ii, rm, ri)) { rm = m; ri = ii; }
        }
        float wm = wave_fmax_bcast(rm);
        unsigned tb = (rm == wm) ? ri : 0u;
        unsigned wi = wave_umax_bcast(tb);
        T2m = wm; T2i = wi;  // new bound on everything outside actives
      }
    }
    sel_cnt = pc;
    total += pc;
  }
}

// ---------------- K2a: wave-per-sample KNN + covariance + eigh -> feats9 ----------------
__global__ __launch_bounds__(256) void k2a_knn(
    const float* __restrict__ pos, const float* __restrict__ col,
    const int* __restrict__ sample_idx,
    float4* __restrict__ sp4g, float* __restrict__ feats9) {
  __shared__ float4 sp[NUM_SAMPLE];
  const int tid = threadIdx.x, lane = tid & 63, wv = tid >> 6;
  for (int i = tid; i < NUM_SAMPLE; i += 256) {
    int idx = sample_idx[i];
    float x = pos[3 * idx], y = pos[3 * idx + 1], z = pos[3 * idx + 2];
    float nrm = addrn(addrn(mulrn(x, x), mulrn(y, y)), mulrn(z, z));
    float4 v = make_float4(x, y, z, nrm);
    sp[i] = v;
    if (blockIdx.x == 0) sp4g[i] = v;
  }
  __syncthreads();
  for (int it = 0; it < 4; ++it) {
    const int r = blockIdx.x * 16 + wv * 4 + it;
    float4 pr = sp[r];
    unsigned long long kk[16];
#pragma unroll
    for (int k = 0; k < 16; ++k) {
      int j = lane + 64 * k;
      float4 q = sp[j];
      float dot = fmaf(pr.z, q.z, fmaf(pr.y, q.y, mulrn(pr.x, q.x)));
      float d2 = subrn(addrn(pr.w, q.w), mulrn(2.f, dot));
      unsigned b = __float_as_uint(d2);
      unsigned sbits = (b & 0x80000000u) ? ~b : (b | 0x80000000u);
      kk[k] = ((unsigned long long)sbits << 32) | (unsigned)j;
    }
    int bi[17];
#pragma unroll
    for (int rsel = 0; rsel < 17; ++rsel) {
      unsigned long long best = 0xFFFFFFFFFFFFFFFFull;
#pragma unroll
      for (int k = 0; k < 16; ++k) best = (kk[k] < best) ? kk[k] : best;
#pragma unroll
      for (int mk = 1; mk < 64; mk <<= 1) {
        unsigned long long o = (unsigned long long)__shfl_xor((long long)best, mk, 64);
        best = (o < best) ? o : best;
      }
      int j = (int)(best & 0xFFFFFFFFull);
      bi[rsel] = j;
#pragma unroll
      for (int k = 0; k < 16; ++k)
        if (((j >> 6) == k) && ((j & 63) == lane)) kk[k] = 0xFFFFFFFFFFFFFFFFull;
    }
    float mx = 0.f, my = 0.f, mz = 0.f;
#pragma unroll
    for (int k = 1; k <= 16; ++k) {
      float4 q = sp[bi[k]];
      mx = addrn(mx, q.x); my = addrn(my, q.y); mz = addrn(mz, q.z);
    }
    mx = mulrn(mx, 0.0625f); my = mulrn(my, 0.0625f); mz = mulrn(mz, 0.0625f);
    float c00 = 0.f, c01 = 0.f, c02 = 0.f, c11 = 0.f, c12 = 0.f, c22 = 0.f;
#pragma unroll
    for (int k = 1; k <= 16; ++k) {
      float4 q = sp[bi[k]];
      float dx = subrn(q.x, mx), dy = subrn(q.y, my), dz = subrn(q.z, mz);
      c00 = addrn(c00, mulrn(dx, dx)); c01 = addrn(c01, mulrn(dx, dy));
      c02 = addrn(c02, mulrn(dx, dz)); c11 = addrn(c11, mulrn(dy, dy));
      c12 = addrn(c12, mulrn(dy, dz)); c22 = addrn(c22, mulrn(dz, dz));
    }
    c00 /= 15.f; c01 /= 15.f; c02 /= 15.f; c11 /= 15.f; c12 /= 15.f; c22 /= 15.f;

    float n0, n1, n2;
    eigh3_smallest(c00, c01, c02, c11, c12, c22, n0, n1, n2);
    float nn = __fsqrt_rn(addrn(addrn(mulrn(n0, n0), mulrn(n1, n1)), mulrn(n2, n2)));
    float den = addrn(nn, 1e-8f);
    n0 /= den; n1 /= den; n2 /= den;

    if (lane == 0) {
      int myidx = sample_idx[r];
      float* f = feats9 + r * 9;
      f[0] = pr.x; f[1] = pr.y; f[2] = pr.z;
      f[3] = col[3 * myidx]; f[4] = col[3 * myidx + 1]; f[5] = col[3 * myidx + 2];
      f[6] = n0; f[7] = n1; f[8] = n2;
    }
  }
}

// ---------------- K2b: per-thread MLP (order identical to passing version) ----------------
__global__ __launch_bounds__(64) void k2b_mlp(
    const float* __restrict__ W1, const float* __restrict__ b1,
    const float* __restrict__ W2, const float* __restrict__ b2,
    const float* __restrict__ W3, const float* __restrict__ b3,
    const float* __restrict__ feats9,
    float* __restrict__ featd, int* __restrict__ lbl) {
  __shared__ float hbuf[64][129];
  const int tid = threadIdx.x;
  const int r = blockIdx.x * 64 + tid;
  float f9[9];
#pragma unroll
  for (int k = 0; k < 9; ++k) f9[k] = feats9[r * 9 + k];
  for (int jo = 0; jo < 128; ++jo) {
    float acc = 0.f;
#pragma unroll
    for (int k = 0; k < 9; ++k) acc = fmaf(f9[k], W1[k * 128 + jo], acc);
    acc += b1[jo];
    hbuf[tid][jo] = fmaxf(acc, 0.f);
  }
  float pd[13];
#pragma unroll
  for (int c = 0; c < 13; ++c) pd[c] = 0.f;
  for (int io = 0; io < 128; io += 16) {
    float acc[16];
#pragma unroll
    for (int t = 0; t < 16; ++t) acc[t] = 0.f;
    for (int j = 0; j < 128; ++j) {
      float hj = hbuf[tid][j];
#pragma unroll
      for (int t = 0; t < 16; ++t) acc[t] = fmaf(hj, W2[j * 128 + io + t], acc[t]);
    }
#pragma unroll
    for (int t = 0; t < 16; ++t) {
      float h2 = fmaxf(acc[t] + b2[io + t], 0.f);
#pragma unroll
      for (int c = 0; c < 13; ++c) pd[c] = fmaf(h2, W3[(io + t) * 13 + c], pd[c]);
    }
  }
#pragma unroll
  for (int c = 0; c < 13; ++c) pd[c] += b3[c];
  float mmax = pd[0];
#pragma unroll
  for (int c = 1; c < 13; ++c) mmax = fmaxf(mmax, pd[c]);
  float es = 0.f, ev[13];
#pragma unroll
  for (int c = 0; c < 13; ++c) { ev[c] = expf(pd[c] - mmax); es += ev[c]; }
#pragma unroll
  for (int c = 0; c < 13; ++c) featd[r * 13 + c] = ev[c] / es;
  int am = 0; float bv = pd[0];
#pragma unroll
  for (int c = 1; c < 13; ++c) { if (pd[c] > bv) { bv = pd[c]; am = c; } }
  lbl[r] = am;
}

// ---------------- K3: nearest sample + gather outputs ----------------
__global__ __launch_bounds__(256) void k3_assign(
    const float* __restrict__ pos,
    const float4* __restrict__ sp4g,
    const float* __restrict__ featd,
    const int* __restrict__ lbl,
    float* __restrict__ out) {
  __shared__ float4 sp[NUM_SAMPLE];
  for (int i = threadIdx.x; i < NUM_SAMPLE; i += 256) sp[i] = sp4g[i];
  __syncthreads();
  int i = blockIdx.x * 256 + threadIdx.x;
  float x = pos[3 * i], y = pos[3 * i + 1], z = pos[3 * i + 2];
  float an = addrn(addrn(mulrn(x, x), mulrn(y, y)), mulrn(z, z));
  float bestd = 3.402823466e+38f; int bestj = 0;
#pragma unroll 4
  for (int j = 0; j < NUM_SAMPLE; ++j) {
    float4 q = sp[j];
    float dot = fmaf(z, q.z, fmaf(y, q.y, mulrn(x, q.x)));
    float d2 = subrn(addrn(an, q.w), mulrn(2.f, dot));
    if (d2 < bestd) { bestd = d2; bestj = j; }
  }
  const float* fr = featd + bestj * 13;
  float* o = out + (size_t)i * 13;
#pragma unroll
  for (int c = 0; c < 13; ++c) o[c] = fr[c];
  out[(size_t)N_TOTAL * 13 + i] = (float)lbl[bestj];
}

extern "C" void kernel_launch(void* const* d_in, const int* in_sizes, int n_in,
                              void* d_out, int out_size, void* d_ws, size_t ws_size,
                              hipStream_t stream) {
  (void)in_sizes; (void)n_in; (void)out_size; (void)ws_size;
  const float* pos = (const float*)d_in[0];
  const float* col = (const float*)d_in[1];
  const float* W1 = (const float*)d_in[2];
  const float* b1 = (const float*)d_in[3];
  const float* W2 = (const float*)d_in[4];
  const float* b2 = (const float*)d_in[5];
  const float* W3 = (const float*)d_in[6];
  const float* b3 = (const float*)d_in[7];
  float* out = (float*)d_out;

  char* w = (char*)d_ws;
  unsigned long long* cand = (unsigned long long*)(w);           // 64 KiB (2 sets x 4096)
  int* sample_idx = (int*)(w + 65536);                           //  4 KiB
  float4* sp4g = (float4*)(w + 73728);                           // 16 KiB
  float* featd = (float*)(w + 90112);                            // 52 KiB
  int* lbl = (int*)(w + 143360);                                 //  4 KiB
  float* feats9 = (float*)(w + 147456);                          // 36 KiB

  k0_init<<<32, 256, 0, stream>>>(cand, sample_idx);
  k1_fps<<<FPS_BLOCKS, FPS_THREADS, 0, stream>>>(pos, cand, sample_idx);
  k2a_knn<<<64, 256, 0, stream>>>(pos, col, sample_idx, sp4g, feats9);
  k2b_mlp<<<16, 64, 0, stream>>>(W1, b1, W2, b2, W3, b3, feats9, featd, lbl);
  k3_assign<<<N_TOTAL / 256, 256, 0, stream>>>(pos, sp4g, featd, lbl, out);
}

// Round 3
// 2326.717 us; speedup vs baseline: 1.1100x; 1.1100x over previous
//
#include <hip/hip_runtime.h>
#include <math.h>

#define N_TOTAL    262144
#define NUM_SAMPLE 1024
#define FPS_BLOCKS 64
#define FPS_THREADS 256
#define FPS_PPT (N_TOTAL / (FPS_BLOCKS * FPS_THREADS))   // 16
#define M_WAVE 8                                          // published cands per wave
#define POOL (FPS_BLOCKS * 4 * M_WAVE)                    // 2048
#define ENT_PER_T (POOL / FPS_THREADS)                    // 8
#define QD (POOL / 64)                                    // 32 register actives/lane (FULL pool)
#define SEL_CAP 1023

__device__ __forceinline__ float addrn(float a, float b) { return __fadd_rn(a, b); }
__device__ __forceinline__ float subrn(float a, float b) { return __fsub_rn(a, b); }
__device__ __forceinline__ float mulrn(float a, float b) { return __fmul_rn(a, b); }

__device__ __forceinline__ float d2rn(float ax, float ay, float az,
                                      float bx, float by, float bz) {
  float dx = subrn(ax, bx), dy = subrn(ay, by), dz = subrn(az, bz);
  return addrn(addrn(mulrn(dx, dx), mulrn(dy, dy)), mulrn(dz, dz));
}

__device__ __forceinline__ bool lex_gt(float m1, unsigned i1, float m2, unsigned i2) {
  return (m1 > m2) || (m1 == m2 && i1 > i2);
}
__device__ __forceinline__ bool lex_ge(float m1, unsigned i1, float m2, unsigned i2) {
  return (m1 > m2) || (m1 == m2 && i1 >= i2);
}

// ---- DPP wave64 max-reduce + SGPR broadcast (no LDS pipe, pure VALU) ----
template <int CTRL>
__device__ __forceinline__ int dpp_i(int x) {
  return __builtin_amdgcn_update_dpp(x, x, CTRL, 0xF, 0xF, false);
}
__device__ __forceinline__ float wave_fmax_bcast(float v) {
  v = fmaxf(v, __int_as_float(dpp_i<0x111>(__float_as_int(v))));   // row_shr:1
  v = fmaxf(v, __int_as_float(dpp_i<0x112>(__float_as_int(v))));   // row_shr:2
  v = fmaxf(v, __int_as_float(dpp_i<0x114>(__float_as_int(v))));   // row_shr:4
  v = fmaxf(v, __int_as_float(dpp_i<0x118>(__float_as_int(v))));   // row_shr:8
  v = fmaxf(v, __int_as_float(dpp_i<0x142>(__float_as_int(v))));   // row_bcast:15
  v = fmaxf(v, __int_as_float(dpp_i<0x143>(__float_as_int(v))));   // row_bcast:31
  return __int_as_float(__builtin_amdgcn_readlane(__float_as_int(v), 63));
}
__device__ __forceinline__ unsigned wave_umax_bcast(unsigned v) {
  unsigned o;
  o = (unsigned)dpp_i<0x111>((int)v); v = (o > v) ? o : v;
  o = (unsigned)dpp_i<0x112>((int)v); v = (o > v) ? o : v;
  o = (unsigned)dpp_i<0x114>((int)v); v = (o > v) ? o : v;
  o = (unsigned)dpp_i<0x118>((int)v); v = (o > v) ? o : v;
  o = (unsigned)dpp_i<0x142>((int)v); v = (o > v) ? o : v;
  o = (unsigned)dpp_i<0x143>((int)v); v = (o > v) ? o : v;
  return (unsigned)__builtin_amdgcn_readlane((int)v, 63);
}

// ---------------- LAPACK emulation (f32) ----------------
__device__ __forceinline__ float slapy2f(float x, float y) {
  float xa = fabsf(x), ya = fabsf(y);
  float w = fmaxf(xa, ya), z = fminf(xa, ya);
  if (z == 0.f) return w;
  float t = z / w;
  return w * __fsqrt_rn(1.f + t * t);
}

__device__ __forceinline__ void slartgf(float f, float g, float& c, float& s, float& r) {
  if (g == 0.f) { c = 1.f; s = 0.f; r = f; }
  else if (f == 0.f) { c = 0.f; s = (g > 0.f) ? 1.f : -1.f; r = fabsf(g); }
  else {
    float d = __fsqrt_rn(f * f + g * g);
    c = fabsf(f) / d;
    r = (f >= 0.f) ? d : -d;
    s = g / r;
  }
}

__device__ void slaev2f(float a, float b, float c0, float& rt1, float& rt2,
                        float& cs1, float& sn1) {
  float sm = a + c0, df = a - c0;
  float adf = fabsf(df), tb = b + b, ab = fabsf(tb);
  float acmx, acmn;
  if (fabsf(a) > fabsf(c0)) { acmx = a; acmn = c0; } else { acmx = c0; acmn = a; }
  float rt;
  if (adf > ab)      { float t = ab / adf; rt = adf * __fsqrt_rn(1.f + t * t); }
  else if (adf < ab) { float t = adf / ab; rt = ab * __fsqrt_rn(1.f + t * t); }
  else               { rt = ab * __fsqrt_rn(2.f); }
  int sgn1;
  if (sm < 0.f)      { rt1 = 0.5f * (sm - rt); sgn1 = -1; rt2 = (acmx / rt1) * acmn - (b / rt1) * b; }
  else if (sm > 0.f) { rt1 = 0.5f * (sm + rt); sgn1 = 1;  rt2 = (acmx / rt1) * acmn - (b / rt1) * b; }
  else               { rt1 = 0.5f * rt; rt2 = -0.5f * rt; sgn1 = 1; }
  float cs; int sgn2;
  if (df >= 0.f) { cs = df + rt; sgn2 = 1; } else { cs = df - rt; sgn2 = -1; }
  float acs = fabsf(cs);
  if (acs > ab) {
    float ct = -tb / cs;
    sn1 = 1.f / __fsqrt_rn(1.f + ct * ct);
    cs1 = ct * sn1;
  } else {
    if (ab == 0.f) { cs1 = 1.f; sn1 = 0.f; }
    else { float tn = -cs / tb; cs1 = 1.f / __fsqrt_rn(1.f + tn * tn); sn1 = tn * cs1; }
  }
  if (sgn1 == sgn2) { float tn = cs1; cs1 = -sn1; sn1 = tn; }
}

#define D_(i) d[(i)-1]
#define E_(i) e[(i)-1]

__device__ void ssteqr3(float d[3], float e[2], float Z[3][3]) {
  const float eps    = 5.9604645e-08f;
  const float eps2   = 3.5527137e-15f;
  const float safmin = 1.17549435e-38f;
  const float ssfmax = 3.0744573e+18f;
  const float ssfmin = 3.0517578e-05f;
  const int n = 3;
  int jtot = 0, nmaxit = 90;
  int l1 = 1;

  while (true) {
    if (l1 > n) break;
    if (l1 > 1) E_(l1 - 1) = 0.f;
    int m = n;
    for (int mm = l1; mm <= n - 1; ++mm) {
      float tst = fabsf(E_(mm));
      if (tst == 0.f) { m = mm; break; }
      if (tst <= (__fsqrt_rn(fabsf(D_(mm))) * __fsqrt_rn(fabsf(D_(mm + 1)))) * eps) {
        E_(mm) = 0.f; m = mm; break;
      }
    }
    int l = l1, lsv = l, lend = m, lendsv = m;
    l1 = m + 1;
    if (lend == l) continue;

    float anorm = fabsf(D_(lend));
    for (int i2 = l; i2 <= lend - 1; ++i2) {
      anorm = fmaxf(anorm, fabsf(D_(i2)));
      anorm = fmaxf(anorm, fabsf(E_(i2)));
    }
    int iscale = 0;
    if (anorm == 0.f) continue;
    if (anorm > ssfmax) {
      iscale = 1; float mul = ssfmax / anorm;
      for (int i2 = l; i2 <= lend; ++i2) D_(i2) *= mul;
      for (int i2 = l; i2 <= lend - 1; ++i2) E_(i2) *= mul;
    } else if (anorm < ssfmin) {
      iscale = 2; float mul = ssfmin / anorm;
      for (int i2 = l; i2 <= lend; ++i2) D_(i2) *= mul;
      for (int i2 = l; i2 <= lend - 1; ++i2) E_(i2) *= mul;
    }

    if (fabsf(D_(lend)) < fabsf(D_(l))) { int t = l; l = lend; lend = t; }

    if (lend > l) {
      while (true) {
        int m2 = lend;
        if (l != lend) {
          for (int mm = l; mm <= lend - 1; ++mm) {
            float tst = fabsf(E_(mm)); tst = tst * tst;
            if (tst <= (eps2 * fabsf(D_(mm))) * fabsf(D_(mm + 1)) + safmin) { m2 = mm; break; }
          }
        }
        if (m2 < lend) E_(m2) = 0.f;
        float p = D_(l);
        if (m2 == l) { D_(l) = p; l = l + 1; if (l <= lend) continue; break; }
        if (m2 == l + 1) {
          float rt1, rt2, cc, ss;
          slaev2f(D_(l), E_(l), D_(l + 1), rt1, rt2, cc, ss);
          for (int i2 = 0; i2 < 3; ++i2) {
            float tmp = Z[i2][l];
            Z[i2][l]     = cc * tmp - ss * Z[i2][l - 1];
            Z[i2][l - 1] = ss * tmp + cc * Z[i2][l - 1];
          }
          D_(l) = rt1; D_(l + 1) = rt2; E_(l) = 0.f;
          l = l + 2; if (l <= lend) continue; break;
        }
        if (jtot == nmaxit) break;
        ++jtot;
        float g = (D_(l + 1) - p) / (2.f * E_(l));
        float r = slapy2f(g, 1.f);
        float sgn_rg = (g >= 0.f) ? r : -r;
        g = D_(m2) - p + E_(l) / (g + sgn_rg);
        float s = 1.f, c = 1.f;
        p = 0.f;
        float csv[2], ssv[2];
        for (int i2 = m2 - 1; i2 >= l; --i2) {
          float f = s * E_(i2);
          float b = c * E_(i2);
          slartgf(g, f, c, s, r);
          if (i2 != m2 - 1) E_(i2 + 1) = r;
          g = D_(i2 + 1) - p;
          r = (D_(i2) - g) * s + 2.f * c * b;
          p = s * r;
          D_(i2 + 1) = g + p;
          g = c * r - b;
          csv[i2 - l] = c; ssv[i2 - l] = -s;
        }
        for (int j = m2 - 1; j >= l; --j) {
          float ct = csv[j - l], st = ssv[j - l];
          for (int i2 = 0; i2 < 3; ++i2) {
            float tmp = Z[i2][j];
            Z[i2][j]     = ct * tmp - st * Z[i2][j - 1];
            Z[i2][j - 1] = st * tmp + ct * Z[i2][j - 1];
          }
        }
        D_(l) = D_(l) - p;
        E_(l) = g;
      }
    } else {
      while (true) {
        int m2 = lend;
        if (l != lend) {
          for (int mm = l; mm >= lend + 1; --mm) {
            float tst = fabsf(E_(mm - 1)); tst = tst * tst;
            if (tst <= (eps2 * fabsf(D_(mm))) * fabsf(D_(mm - 1)) + safmin) { m2 = mm; break; }
          }
        }
        if (m2 > lend) E_(m2 - 1) = 0.f;
        float p = D_(l);
        if (m2 == l) { D_(l) = p; l = l - 1; if (l >= lend) continue; break; }
        if (m2 == l - 1) {
          float rt1, rt2, cc, ss;
          slaev2f(D_(l - 1), E_(l - 1), D_(l), rt1, rt2, cc, ss);
          for (int i2 = 0; i2 < 3; ++i2) {
            float tmp = Z[i2][l - 1];
            Z[i2][l - 1] = cc * tmp - ss * Z[i2][l - 2];
            Z[i2][l - 2] = ss * tmp + cc * Z[i2][l - 2];
          }
          D_(l - 1) = rt1; D_(l) = rt2; E_(l - 1) = 0.f;
          l = l - 2; if (l >= lend) continue; break;
        }
        if (jtot == nmaxit) break;
        ++jtot;
        float g = (D_(l - 1) - p) / (2.f * E_(l - 1));
        float r = slapy2f(g, 1.f);
        float sgn_rg = (g >= 0.f) ? r : -r;
        g = D_(m2) - p + E_(l - 1) / (g + sgn_rg);
        float s = 1.f, c = 1.f;
        p = 0.f;
        float csv[2], ssv[2];
        for (int i2 = m2; i2 <= l - 1; ++i2) {
          float f = s * E_(i2);
          float b = c * E_(i2);
          slartgf(g, f, c, s, r);
          if (i2 != m2) E_(i2 - 1) = r;
          g = D_(i2) - p;
          r = (D_(i2 + 1) - g) * s + 2.f * c * b;
          p = s * r;
          D_(i2) = g + p;
          g = c * r - b;
          csv[i2 - m2] = c; ssv[i2 - m2] = s;
        }
        for (int j = m2; j <= l - 1; ++j) {
          float ct = csv[j - m2], st = ssv[j - m2];
          for (int i2 = 0; i2 < 3; ++i2) {
            float tmp = Z[i2][j];
            Z[i2][j]     = ct * tmp - st * Z[i2][j - 1];
            Z[i2][j - 1] = st * tmp + ct * Z[i2][j - 1];
          }
        }
        D_(l) = D_(l) - p;
        E_(l - 1) = g;
      }
    }
    if (iscale == 1) {
      float mul = anorm / ssfmax;
      for (int i2 = lsv; i2 <= lendsv; ++i2) D_(i2) *= mul;
      for (int i2 = lsv; i2 <= lendsv - 1; ++i2) E_(i2) *= mul;
    } else if (iscale == 2) {
      float mul = anorm / ssfmin;
      for (int i2 = lsv; i2 <= lendsv; ++i2) D_(i2) *= mul;
      for (int i2 = lsv; i2 <= lendsv - 1; ++i2) E_(i2) *= mul;
    }
  }
  for (int ii = 2; ii <= n; ++ii) {
    int i2 = ii - 1, k = i2;
    float p = D_(i2);
    for (int j = ii; j <= n; ++j) if (D_(j) < p) { k = j; p = D_(j); }
    if (k != i2) {
      D_(k) = D_(i2); D_(i2) = p;
      for (int rr = 0; rr < 3; ++rr) {
        float t = Z[rr][i2 - 1]; Z[rr][i2 - 1] = Z[rr][k - 1]; Z[rr][k - 1] = t;
      }
    }
  }
}

__device__ void eigh3_smallest(float a00, float a10, float a20, float a11, float a21, float a22,
                               float& nx, float& ny, float& nz) {
  float d[3], e[2];
  float Z[3][3] = {{1.f,0.f,0.f},{0.f,1.f,0.f},{0.f,0.f,1.f}};
  float tau, v2;
  {
    float alpha = a10, x = a20;
    float xnorm = fabsf(x);
    if (xnorm == 0.f) {
      tau = 0.f; v2 = 0.f;
      d[0] = a00; d[1] = a11; d[2] = a22;
      e[0] = alpha; e[1] = a21;
    } else {
      float beta = -copysignf(slapy2f(alpha, x), alpha);
      tau = (beta - alpha) / beta;
      v2 = x / (alpha - beta);
      float w0 = (tau * a11) + tau * (a21 * v2);
      float w1 = (tau * a21) + (tau * v2) * a22;
      float ac = (-0.5f * tau) * (w0 + w1 * v2);
      w0 = w0 + ac;
      w1 = w1 + ac * v2;
      d[0] = a00;
      d[1] = (a11 - w0) - w0;
      d[2] = (a22 - v2 * w1) - w1 * v2;
      e[0] = beta;
      e[1] = (a21 - v2 * w0) - w1;
    }
  }
  ssteqr3(d, e, Z);
  if (tau != 0.f) {
    for (int c = 0; c < 3; ++c) {
      float w = Z[1][c] + Z[2][c] * v2;
      float temp = (-tau) * w;
      Z[1][c] = Z[1][c] + temp;
      Z[2][c] = Z[2][c] + v2 * temp;
    }
  }
  nx = Z[0][0]; ny = Z[1][0]; nz = Z[2][0];
}

// ---------------- K0: init workspace ----------------
__global__ void k0_init(unsigned long long* cand, int* sample_idx) {
  int t = blockIdx.x * blockDim.x + threadIdx.x;
  if (t < 2 * POOL) cand[t] = 0ull;
  if (t == 0) sample_idx[0] = 0;
}

// ---------------- K1: batched FPS ----------------
// Round-2 post-mortem: batches are pinned at ~22 regardless of published
// depth (WRITE_SIZE proof), and round-1's residual ~35us/batch was REFILL
// STORMS (T2 at rank ~73 in a value-bunched md field -> refill every ~2
// picks, each 2 barriers). This version removes refills BY CONSTRUCTION:
// the ENTIRE pool (2048 = 32/lane) lives in wave0 registers, so the active
// max is always the exact pool max. No T2, no refill path, no event loop;
// one barrier pair per batch. Per pick: fused min-update+argmax over 32
// register entries (issue-bound), one DPP lex-max chain, winner coords via
// one uniform ds_read_b128 broadcast from the act4 LDS copy.
// Exactness: pool = every wave's top-8 (lex-descending); any unpublished
// point <lex its wave's 8th <=lex Tmd; pool entries are min-updated exactly
// vs every in-batch pick (winner self-kills via d2=0); pick while winner
// >=lex Tmd. Ties broken by idf = 0x3FFFFF - index (larger idf == smaller
// original index == reference argmax-first semantics).
__global__ __launch_bounds__(FPS_THREADS, 1) void k1_fps(
    const float* __restrict__ pos,
    unsigned long long* __restrict__ cand,
    int* __restrict__ sample_idx) {
  __shared__ float4 sel4[SEL_CAP];
  __shared__ float4 act4[POOL];          // (x,y,z,md) per pool entry
  __shared__ unsigned act_idf[POOL];
  __shared__ float thrT_md[FPS_THREADS];     // per-thread 8th-best (Tmd source)
  __shared__ unsigned thrT_idf[FPS_THREADS];
  __shared__ int sh_pc;

  const int tidx = threadIdx.x;
  const int lane = tidx & 63;
  const int gtid = blockIdx.x * FPS_THREADS + tidx;

  float px[FPS_PPT], py[FPS_PPT], pz[FPS_PPT], md[FPS_PPT];
#pragma unroll
  for (int k = 0; k < FPS_PPT; ++k) {
    int p = gtid + k * (FPS_BLOCKS * FPS_THREADS);
    px[k] = pos[3 * p]; py[k] = pos[3 * p + 1]; pz[k] = pos[3 * p + 2];
    md[k] = 1e10f;
  }
  const unsigned idf0 = 0x3FFFFFu - (unsigned)gtid;
  if (tidx == 0) sel4[0] = make_float4(pos[0], pos[1], pos[2], 0.f);
  __syncthreads();
  int sel_cnt = 1, total = 0, bt = 0;
  while (total < NUM_SAMPLE - 1) {
    ++bt;
    // ---- Phase A: owner md updates vs previous batch's picks (pipelined) ----
    {
      float4 sc = sel4[0];
      for (int s = 0; s < sel_cnt; ++s) {
        float4 sn = (s + 1 < sel_cnt) ? sel4[s + 1] : sc;
#pragma unroll
        for (int k = 0; k < FPS_PPT; ++k)
          md[k] = fminf(md[k], d2rn(px[k], py[k], pz[k], sc.x, sc.y, sc.z));
        sc = sn;
      }
    }
    // ---- per-wave top-8 via DPP (registers only, barrier-free) ----
    const unsigned tag = (unsigned)bt & 1023u;
    unsigned long long* setbase = cand + (size_t)(bt & 1) * POOL;
    {
      const int wv = tidx >> 6;
      float wmd[FPS_PPT];
#pragma unroll
      for (int k = 0; k < FPS_PPT; ++k) wmd[k] = md[k];
      unsigned long long mypub = 0ull;
      for (int r = 0; r < M_WAVE; ++r) {
        float bm = wmd[0]; unsigned bidf = idf0;
#pragma unroll
        for (int k = 1; k < FPS_PPT; ++k) {
          unsigned idfk = idf0 - ((unsigned)k << 14);
          if (wmd[k] > bm || (wmd[k] == bm && idfk > bidf)) { bm = wmd[k]; bidf = idfk; }
        }
        float wmx = wave_fmax_bcast(bm);
        unsigned tb = (bm == wmx) ? bidf : 0u;
        unsigned widf = wave_umax_bcast(tb);
        if (lane == r)
          mypub = ((unsigned long long)__float_as_uint(wmx) << 32) |
                  ((unsigned long long)widf << 10);
#pragma unroll
        for (int k = 0; k < FPS_PPT; ++k) {
          unsigned idfk = idf0 - ((unsigned)k << 14);
          if (wmd[k] == wmx && idfk == widf) wmd[k] = -1.f;
        }
      }
      if (lane < M_WAVE)
        __hip_atomic_store(setbase + blockIdx.x * (4 * M_WAVE) + (tidx >> 6) * M_WAVE + lane,
                           mypub | tag, __ATOMIC_RELAXED, __HIP_MEMORY_SCOPE_AGENT);
    }
    // ---- Phase B: poll own 8 words; gather xyz inline as tags arrive ----
    const int base_w = tidx * ENT_PER_T;
    {
      float cmd[ENT_PER_T]; unsigned cidf[ENT_PER_T];
      float cx[ENT_PER_T], cy[ENT_PER_T], cz[ENT_PER_T];
      unsigned done = 0;
      while (done != 0xFFu) {
#pragma unroll
        for (int j = 0; j < ENT_PER_T; ++j) {
          if (!((done >> j) & 1u)) {
            unsigned long long v = __hip_atomic_load(setbase + base_w + j,
                                                     __ATOMIC_RELAXED, __HIP_MEMORY_SCOPE_AGENT);
            if ((unsigned)(v & 1023ull) == tag) {
              done |= 1u << j;
              cmd[j] = __uint_as_float((unsigned)(v >> 32));
              cidf[j] = (unsigned)((v >> 10) & 0x3FFFFFull);
              int gidx = 0x3FFFFF - (int)cidf[j];
              cx[j] = pos[3 * gidx]; cy[j] = pos[3 * gidx + 1]; cz[j] = pos[3 * gidx + 2];
            }
          }
        }
        if (done != 0xFFu) __builtin_amdgcn_s_sleep(1);
      }
      // ---- handoff: full pool into LDS + Tmd source ----
#pragma unroll
      for (int j = 0; j < ENT_PER_T; ++j) {
        int e = tidx * ENT_PER_T + j;
        act4[e] = make_float4(cx[j], cy[j], cz[j], cmd[j]);
        act_idf[e] = cidf[j];
      }
      thrT_md[tidx] = cmd[ENT_PER_T - 1]; thrT_idf[tidx] = cidf[ENT_PER_T - 1];
    }
    __syncthreads();
    const int room = (NUM_SAMPLE - 1) - total;
    // ---- wave0: register-resident FULL pool, pick to batch end, no refills ----
    if (tidx < 64) {
      float q_md[QD], q_x[QD], q_y[QD], q_z[QD];
      unsigned q_idf[QD];
#pragma unroll
      for (int r = 0; r < QD; ++r) {
        int e2 = lane + 64 * r;
        float4 a = act4[e2];
        q_x[r] = a.x; q_y[r] = a.y; q_z[r] = a.z; q_md[r] = a.w;
        q_idf[r] = act_idf[e2];
      }
      // Tmd = lex-max over 256 pool-waves of their 8th-best
      float rm = thrT_md[lane]; unsigned ri = thrT_idf[lane];
#pragma unroll
      for (int r = 1; r < 4; ++r) {
        float m = thrT_md[lane + 64 * r]; unsigned ii = thrT_idf[lane + 64 * r];
        if (lex_gt(m, ii, rm, ri)) { rm = m; ri = ii; }
      }
      float Tmd = wave_fmax_bcast(rm);
      unsigned tbT = (rm == Tmd) ? ri : 0u;
      unsigned Tidf = wave_umax_bcast(tbT);

      int picks = 0;
      float X = 1e30f, Y = 1e30f, Z = 1e30f;   // priming: d2 -> inf, fmin no-op
      for (;;) {
        // fused: apply last pick's suppression + local lex-argmax
        float bm = -1.f; unsigned bidf = 0u; int bj = 0;
#pragma unroll
        for (int j = 0; j < QD; ++j) {
          float nd = fminf(q_md[j], d2rn(q_x[j], q_y[j], q_z[j], X, Y, Z));
          q_md[j] = nd;
          if (lex_gt(nd, q_idf[j], bm, bidf)) { bm = nd; bidf = q_idf[j]; bj = j; }
        }
        float wmx = wave_fmax_bcast(bm);
        unsigned long long ball = __ballot(bm == wmx);
        unsigned widf; int owner;
        if (__builtin_popcountll(ball) == 1) {
          owner = __builtin_ctzll(ball);
          widf = (unsigned)__builtin_amdgcn_readlane((int)bidf, owner);
        } else {  // md tie across lanes: rare exact-tiebreak path
          unsigned tb = (bm == wmx) ? bidf : 0u;
          widf = wave_umax_bcast(tb);
          owner = __builtin_ctzll(__ballot(bm == wmx && bidf == widf));
        }
        if (picks >= room) break;
        if (!lex_ge(wmx, widf, Tmd, Tidf)) break;   // batch done
        int bjo = __builtin_amdgcn_readlane(bj, owner);
        float4 wc = act4[owner + 64 * bjo];          // uniform broadcast read
        X = wc.x; Y = wc.y; Z = wc.z;
        if (lane == 0) {
          sel4[picks] = make_float4(X, Y, Z, 0.f);
          if (blockIdx.x == 0) sample_idx[1 + total + picks] = 0x3FFFFF - (int)widf;
        }
        ++picks;
      }
      if (lane == 0) sh_pc = picks;
    }
    __syncthreads();
    sel_cnt = sh_pc;
    total += sel_cnt;
  }
}

// ---------------- K2a: wave-per-sample KNN + covariance + eigh -> feats9 ----------------
__global__ __launch_bounds__(256) void k2a_knn(
    const float* __restrict__ pos, const float* __restrict__ col,
    const int* __restrict__ sample_idx,
    float4* __restrict__ sp4g, float* __restrict__ feats9) {
  __shared__ float4 sp[NUM_SAMPLE];
  const int tid = threadIdx.x, lane = tid & 63, wv = tid >> 6;
  for (int i = tid; i < NUM_SAMPLE; i += 256) {
    int idx = sample_idx[i];
    float x = pos[3 * idx], y = pos[3 * idx + 1], z = pos[3 * idx + 2];
    float nrm = addrn(addrn(mulrn(x, x), mulrn(y, y)), mulrn(z, z));
    float4 v = make_float4(x, y, z, nrm);
    sp[i] = v;
    if (blockIdx.x == 0) sp4g[i] = v;
  }
  __syncthreads();
  for (int it = 0; it < 4; ++it) {
    const int r = blockIdx.x * 16 + wv * 4 + it;
    float4 pr = sp[r];
    unsigned long long kk[16];
#pragma unroll
    for (int k = 0; k < 16; ++k) {
      int j = lane + 64 * k;
      float4 q = sp[j];
      float dot = fmaf(pr.z, q.z, fmaf(pr.y, q.y, mulrn(pr.x, q.x)));
      float d2 = subrn(addrn(pr.w, q.w), mulrn(2.f, dot));
      unsigned b = __float_as_uint(d2);
      unsigned sbits = (b & 0x80000000u) ? ~b : (b | 0x80000000u);
      kk[k] = ((unsigned long long)sbits << 32) | (unsigned)j;
    }
    int bi[17];
#pragma unroll
    for (int rsel = 0; rsel < 17; ++rsel) {
      unsigned long long best = 0xFFFFFFFFFFFFFFFFull;
#pragma unroll
      for (int k = 0; k < 16; ++k) best = (kk[k] < best) ? kk[k] : best;
#pragma unroll
      for (int mk = 1; mk < 64; mk <<= 1) {
        unsigned long long o = (unsigned long long)__shfl_xor((long long)best, mk, 64);
        best = (o < best) ? o : best;
      }
      int j = (int)(best & 0xFFFFFFFFull);
      bi[rsel] = j;
#pragma unroll
      for (int k = 0; k < 16; ++k)
        if (((j >> 6) == k) && ((j & 63) == lane)) kk[k] = 0xFFFFFFFFFFFFFFFFull;
    }
    float mx = 0.f, my = 0.f, mz = 0.f;
#pragma unroll
    for (int k = 1; k <= 16; ++k) {
      float4 q = sp[bi[k]];
      mx = addrn(mx, q.x); my = addrn(my, q.y); mz = addrn(mz, q.z);
    }
    mx = mulrn(mx, 0.0625f); my = mulrn(my, 0.0625f); mz = mulrn(mz, 0.0625f);
    float c00 = 0.f, c01 = 0.f, c02 = 0.f, c11 = 0.f, c12 = 0.f, c22 = 0.f;
#pragma unroll
    for (int k = 1; k <= 16; ++k) {
      float4 q = sp[bi[k]];
      float dx = subrn(q.x, mx), dy = subrn(q.y, my), dz = subrn(q.z, mz);
      c00 = addrn(c00, mulrn(dx, dx)); c01 = addrn(c01, mulrn(dx, dy));
      c02 = addrn(c02, mulrn(dx, dz)); c11 = addrn(c11, mulrn(dy, dy));
      c12 = addrn(c12, mulrn(dy, dz)); c22 = addrn(c22, mulrn(dz, dz));
    }
    c00 /= 15.f; c01 /= 15.f; c02 /= 15.f; c11 /= 15.f; c12 /= 15.f; c22 /= 15.f;

    float n0, n1, n2;
    eigh3_smallest(c00, c01, c02, c11, c12, c22, n0, n1, n2);
    float nn = __fsqrt_rn(addrn(addrn(mulrn(n0, n0), mulrn(n1, n1)), mulrn(n2, n2)));
    float den = addrn(nn, 1e-8f);
    n0 /= den; n1 /= den; n2 /= den;

    if (lane == 0) {
      int myidx = sample_idx[r];
      float* f = feats9 + r * 9;
      f[0] = pr.x; f[1] = pr.y; f[2] = pr.z;
      f[3] = col[3 * myidx]; f[4] = col[3 * myidx + 1]; f[5] = col[3 * myidx + 2];
      f[6] = n0; f[7] = n1; f[8] = n2;
    }
  }
}

// ---------------- K2b: per-thread MLP (order identical to passing version) ----------------
__global__ __launch_bounds__(64) void k2b_mlp(
    const float* __restrict__ W1, const float* __restrict__ b1,
    const float* __restrict__ W2, const float* __restrict__ b2,
    const float* __restrict__ W3, const float* __restrict__ b3,
    const float* __restrict__ feats9,
    float* __restrict__ featd, int* __restrict__ lbl) {
  __shared__ float hbuf[64][129];
  const int tid = threadIdx.x;
  const int r = blockIdx.x * 64 + tid;
  float f9[9];
#pragma unroll
  for (int k = 0; k < 9; ++k) f9[k] = feats9[r * 9 + k];
  for (int jo = 0; jo < 128; ++jo) {
    float acc = 0.f;
#pragma unroll
    for (int k = 0; k < 9; ++k) acc = fmaf(f9[k], W1[k * 128 + jo], acc);
    acc += b1[jo];
    hbuf[tid][jo] = fmaxf(acc, 0.f);
  }
  float pd[13];
#pragma unroll
  for (int c = 0; c < 13; ++c) pd[c] = 0.f;
  for (int io = 0; io < 128; io += 16) {
    float acc[16];
#pragma unroll
    for (int t = 0; t < 16; ++t) acc[t] = 0.f;
    for (int j = 0; j < 128; ++j) {
      float hj = hbuf[tid][j];
#pragma unroll
      for (int t = 0; t < 16; ++t) acc[t] = fmaf(hj, W2[j * 128 + io + t], acc[t]);
    }
#pragma unroll
    for (int t = 0; t < 16; ++t) {
      float h2 = fmaxf(acc[t] + b2[io + t], 0.f);
#pragma unroll
      for (int c = 0; c < 13; ++c) pd[c] = fmaf(h2, W3[(io + t) * 13 + c], pd[c]);
    }
  }
#pragma unroll
  for (int c = 0; c < 13; ++c) pd[c] += b3[c];
  float mmax = pd[0];
#pragma unroll
  for (int c = 1; c < 13; ++c) mmax = fmaxf(mmax, pd[c]);
  float es = 0.f, ev[13];
#pragma unroll
  for (int c = 0; c < 13; ++c) { ev[c] = expf(pd[c] - mmax); es += ev[c]; }
#pragma unroll
  for (int c = 0; c < 13; ++c) featd[r * 13 + c] = ev[c] / es;
  int am = 0; float bv = pd[0];
#pragma unroll
  for (int c = 1; c < 13; ++c) { if (pd[c] > bv) { bv = pd[c]; am = c; } }
  lbl[r] = am;
}

// ---------------- K3: nearest sample + gather outputs ----------------
__global__ __launch_bounds__(256) void k3_assign(
    const float* __restrict__ pos,
    const float4* __restrict__ sp4g,
    const float* __restrict__ featd,
    const int* __restrict__ lbl,
    float* __restrict__ out) {
  __shared__ float4 sp[NUM_SAMPLE];
  for (int i = threadIdx.x; i < NUM_SAMPLE; i += 256) sp[i] = sp4g[i];
  __syncthreads();
  int i = blockIdx.x * 256 + threadIdx.x;
  float x = pos[3 * i], y = pos[3 * i + 1], z = pos[3 * i + 2];
  float an = addrn(addrn(mulrn(x, x), mulrn(y, y)), mulrn(z, z));
  float bestd = 3.402823466e+38f; int bestj = 0;
#pragma unroll 4
  for (int j = 0; j < NUM_SAMPLE; ++j) {
    float4 q = sp[j];
    float dot = fmaf(z, q.z, fmaf(y, q.y, mulrn(x, q.x)));
    float d2 = subrn(addrn(an, q.w), mulrn(2.f, dot));
    if (d2 < bestd) { bestd = d2; bestj = j; }
  }
  const float* fr = featd + bestj * 13;
  float* o = out + (size_t)i * 13;
#pragma unroll
  for (int c = 0; c < 13; ++c) o[c] = fr[c];
  out[(size_t)N_TOTAL * 13 + i] = (float)lbl[bestj];
}

extern "C" void kernel_launch(void* const* d_in, const int* in_sizes, int n_in,
                              void* d_out, int out_size, void* d_ws, size_t ws_size,
                              hipStream_t stream) {
  (void)in_sizes; (void)n_in; (void)out_size; (void)ws_size;
  const float* pos = (const float*)d_in[0];
  const float* col = (const float*)d_in[1];
  const float* W1 = (const float*)d_in[2];
  const float* b1 = (const float*)d_in[3];
  const float* W2 = (const float*)d_in[4];
  const float* b2 = (const float*)d_in[5];
  const float* W3 = (const float*)d_in[6];
  const float* b3 = (const float*)d_in[7];
  float* out = (float*)d_out;

  char* w = (char*)d_ws;
  unsigned long long* cand = (unsigned long long*)(w);           // 32 KiB (2 sets x 2048)
  int* sample_idx = (int*)(w + 65536);                           //  4 KiB
  float4* sp4g = (float4*)(w + 73728);                           // 16 KiB
  float* featd = (float*)(w + 90112);                            // 52 KiB
  int* lbl = (int*)(w + 143360);                                 //  4 KiB
  float* feats9 = (float*)(w + 147456);                          // 36 KiB

  k0_init<<<16, 256, 0, stream>>>(cand, sample_idx);
  k1_fps<<<FPS_BLOCKS, FPS_THREADS, 0, stream>>>(pos, cand, sample_idx);
  k2a_knn<<<64, 256, 0, stream>>>(pos, col, sample_idx, sp4g, feats9);
  k2b_mlp<<<16, 64, 0, stream>>>(W1, b1, W2, b2, W3, b3, feats9, featd, lbl);
  k3_assign<<<N_TOTAL / 256, 256, 0, stream>>>(pos, sp4g, featd, lbl, out);
}

// Round 4
// 1705.156 us; speedup vs baseline: 1.5146x; 1.3645x over previous
//
#include <hip/hip_runtime.h>
#include <math.h>

#define N_TOTAL    262144
#define NUM_SAMPLE 1024
#define FPS_BLOCKS 64
#define FPS_THREADS 256
#define FPS_PPT (N_TOTAL / (FPS_BLOCKS * FPS_THREADS))   // 16
#define M_WAVE 4                                          // published cands per wave
#define POOL (FPS_BLOCKS * 4 * M_WAVE)                    // 1024
#define ENT_PER_T (POOL / FPS_THREADS)                    // 4
#define QD (POOL / 64)                                    // 16 register entries/lane = FULL pool
#define SEL_CAP 1023

__device__ __forceinline__ float addrn(float a, float b) { return __fadd_rn(a, b); }
__device__ __forceinline__ float subrn(float a, float b) { return __fsub_rn(a, b); }
__device__ __forceinline__ float mulrn(float a, float b) { return __fmul_rn(a, b); }

__device__ __forceinline__ float d2rn(float ax, float ay, float az,
                                      float bx, float by, float bz) {
  float dx = subrn(ax, bx), dy = subrn(ay, by), dz = subrn(az, bz);
  return addrn(addrn(mulrn(dx, dx), mulrn(dy, dy)), mulrn(dz, dz));
}

__device__ __forceinline__ bool lex_gt(float m1, unsigned i1, float m2, unsigned i2) {
  return (m1 > m2) || (m1 == m2 && i1 > i2);
}
__device__ __forceinline__ bool lex_ge(float m1, unsigned i1, float m2, unsigned i2) {
  return (m1 > m2) || (m1 == m2 && i1 >= i2);
}

// ---- DPP wave64 max-reduce + SGPR broadcast (no LDS pipe, pure VALU) ----
template <int CTRL>
__device__ __forceinline__ int dpp_i(int x) {
  return __builtin_amdgcn_update_dpp(x, x, CTRL, 0xF, 0xF, false);
}
__device__ __forceinline__ float wave_fmax_bcast(float v) {
  v = fmaxf(v, __int_as_float(dpp_i<0x111>(__float_as_int(v))));   // row_shr:1
  v = fmaxf(v, __int_as_float(dpp_i<0x112>(__float_as_int(v))));   // row_shr:2
  v = fmaxf(v, __int_as_float(dpp_i<0x114>(__float_as_int(v))));   // row_shr:4
  v = fmaxf(v, __int_as_float(dpp_i<0x118>(__float_as_int(v))));   // row_shr:8
  v = fmaxf(v, __int_as_float(dpp_i<0x142>(__float_as_int(v))));   // row_bcast:15
  v = fmaxf(v, __int_as_float(dpp_i<0x143>(__float_as_int(v))));   // row_bcast:31
  return __int_as_float(__builtin_amdgcn_readlane(__float_as_int(v), 63));
}
__device__ __forceinline__ unsigned wave_umax_bcast(unsigned v) {
  unsigned o;
  o = (unsigned)dpp_i<0x111>((int)v); v = (o > v) ? o : v;
  o = (unsigned)dpp_i<0x112>((int)v); v = (o > v) ? o : v;
  o = (unsigned)dpp_i<0x114>((int)v); v = (o > v) ? o : v;
  o = (unsigned)dpp_i<0x118>((int)v); v = (o > v) ? o : v;
  o = (unsigned)dpp_i<0x142>((int)v); v = (o > v) ? o : v;
  o = (unsigned)dpp_i<0x143>((int)v); v = (o > v) ? o : v;
  return (unsigned)__builtin_amdgcn_readlane((int)v, 63);
}

// ---------------- LAPACK emulation (f32) ----------------
__device__ __forceinline__ float slapy2f(float x, float y) {
  float xa = fabsf(x), ya = fabsf(y);
  float w = fmaxf(xa, ya), z = fminf(xa, ya);
  if (z == 0.f) return w;
  float t = z / w;
  return w * __fsqrt_rn(1.f + t * t);
}

__device__ __forceinline__ void slartgf(float f, float g, float& c, float& s, float& r) {
  if (g == 0.f) { c = 1.f; s = 0.f; r = f; }
  else if (f == 0.f) { c = 0.f; s = (g > 0.f) ? 1.f : -1.f; r = fabsf(g); }
  else {
    float d = __fsqrt_rn(f * f + g * g);
    c = fabsf(f) / d;
    r = (f >= 0.f) ? d : -d;
    s = g / r;
  }
}

__device__ void slaev2f(float a, float b, float c0, float& rt1, float& rt2,
                        float& cs1, float& sn1) {
  float sm = a + c0, df = a - c0;
  float adf = fabsf(df), tb = b + b, ab = fabsf(tb);
  float acmx, acmn;
  if (fabsf(a) > fabsf(c0)) { acmx = a; acmn = c0; } else { acmx = c0; acmn = a; }
  float rt;
  if (adf > ab)      { float t = ab / adf; rt = adf * __fsqrt_rn(1.f + t * t); }
  else if (adf < ab) { float t = adf / ab; rt = ab * __fsqrt_rn(1.f + t * t); }
  else               { rt = ab * __fsqrt_rn(2.f); }
  int sgn1;
  if (sm < 0.f)      { rt1 = 0.5f * (sm - rt); sgn1 = -1; rt2 = (acmx / rt1) * acmn - (b / rt1) * b; }
  else if (sm > 0.f) { rt1 = 0.5f * (sm + rt); sgn1 = 1;  rt2 = (acmx / rt1) * acmn - (b / rt1) * b; }
  else               { rt1 = 0.5f * rt; rt2 = -0.5f * rt; sgn1 = 1; }
  float cs; int sgn2;
  if (df >= 0.f) { cs = df + rt; sgn2 = 1; } else { cs = df - rt; sgn2 = -1; }
  float acs = fabsf(cs);
  if (acs > ab) {
    float ct = -tb / cs;
    sn1 = 1.f / __fsqrt_rn(1.f + ct * ct);
    cs1 = ct * sn1;
  } else {
    if (ab == 0.f) { cs1 = 1.f; sn1 = 0.f; }
    else { float tn = -cs / tb; cs1 = 1.f / __fsqrt_rn(1.f + tn * tn); sn1 = tn * cs1; }
  }
  if (sgn1 == sgn2) { float tn = cs1; cs1 = -sn1; sn1 = tn; }
}

#define D_(i) d[(i)-1]
#define E_(i) e[(i)-1]

__device__ void ssteqr3(float d[3], float e[2], float Z[3][3]) {
  const float eps    = 5.9604645e-08f;
  const float eps2   = 3.5527137e-15f;
  const float safmin = 1.17549435e-38f;
  const float ssfmax = 3.0744573e+18f;
  const float ssfmin = 3.0517578e-05f;
  const int n = 3;
  int jtot = 0, nmaxit = 90;
  int l1 = 1;

  while (true) {
    if (l1 > n) break;
    if (l1 > 1) E_(l1 - 1) = 0.f;
    int m = n;
    for (int mm = l1; mm <= n - 1; ++mm) {
      float tst = fabsf(E_(mm));
      if (tst == 0.f) { m = mm; break; }
      if (tst <= (__fsqrt_rn(fabsf(D_(mm))) * __fsqrt_rn(fabsf(D_(mm + 1)))) * eps) {
        E_(mm) = 0.f; m = mm; break;
      }
    }
    int l = l1, lsv = l, lend = m, lendsv = m;
    l1 = m + 1;
    if (lend == l) continue;

    float anorm = fabsf(D_(lend));
    for (int i2 = l; i2 <= lend - 1; ++i2) {
      anorm = fmaxf(anorm, fabsf(D_(i2)));
      anorm = fmaxf(anorm, fabsf(E_(i2)));
    }
    int iscale = 0;
    if (anorm == 0.f) continue;
    if (anorm > ssfmax) {
      iscale = 1; float mul = ssfmax / anorm;
      for (int i2 = l; i2 <= lend; ++i2) D_(i2) *= mul;
      for (int i2 = l; i2 <= lend - 1; ++i2) E_(i2) *= mul;
    } else if (anorm < ssfmin) {
      iscale = 2; float mul = ssfmin / anorm;
      for (int i2 = l; i2 <= lend; ++i2) D_(i2) *= mul;
      for (int i2 = l; i2 <= lend - 1; ++i2) E_(i2) *= mul;
    }

    if (fabsf(D_(lend)) < fabsf(D_(l))) { int t = l; l = lend; lend = t; }

    if (lend > l) {
      while (true) {
        int m2 = lend;
        if (l != lend) {
          for (int mm = l; mm <= lend - 1; ++mm) {
            float tst = fabsf(E_(mm)); tst = tst * tst;
            if (tst <= (eps2 * fabsf(D_(mm))) * fabsf(D_(mm + 1)) + safmin) { m2 = mm; break; }
          }
        }
        if (m2 < lend) E_(m2) = 0.f;
        float p = D_(l);
        if (m2 == l) { D_(l) = p; l = l + 1; if (l <= lend) continue; break; }
        if (m2 == l + 1) {
          float rt1, rt2, cc, ss;
          slaev2f(D_(l), E_(l), D_(l + 1), rt1, rt2, cc, ss);
          for (int i2 = 0; i2 < 3; ++i2) {
            float tmp = Z[i2][l];
            Z[i2][l]     = cc * tmp - ss * Z[i2][l - 1];
            Z[i2][l - 1] = ss * tmp + cc * Z[i2][l - 1];
          }
          D_(l) = rt1; D_(l + 1) = rt2; E_(l) = 0.f;
          l = l + 2; if (l <= lend) continue; break;
        }
        if (jtot == nmaxit) break;
        ++jtot;
        float g = (D_(l + 1) - p) / (2.f * E_(l));
        float r = slapy2f(g, 1.f);
        float sgn_rg = (g >= 0.f) ? r : -r;
        g = D_(m2) - p + E_(l) / (g + sgn_rg);
        float s = 1.f, c = 1.f;
        p = 0.f;
        float csv[2], ssv[2];
        for (int i2 = m2 - 1; i2 >= l; --i2) {
          float f = s * E_(i2);
          float b = c * E_(i2);
          slartgf(g, f, c, s, r);
          if (i2 != m2 - 1) E_(i2 + 1) = r;
          g = D_(i2 + 1) - p;
          r = (D_(i2) - g) * s + 2.f * c * b;
          p = s * r;
          D_(i2 + 1) = g + p;
          g = c * r - b;
          csv[i2 - l] = c; ssv[i2 - l] = -s;
        }
        for (int j = m2 - 1; j >= l; --j) {
          float ct = csv[j - l], st = ssv[j - l];
          for (int i2 = 0; i2 < 3; ++i2) {
            float tmp = Z[i2][j];
            Z[i2][j]     = ct * tmp - st * Z[i2][j - 1];
            Z[i2][j - 1] = st * tmp + ct * Z[i2][j - 1];
          }
        }
        D_(l) = D_(l) - p;
        E_(l) = g;
      }
    } else {
      while (true) {
        int m2 = lend;
        if (l != lend) {
          for (int mm = l; mm >= lend + 1; --mm) {
            float tst = fabsf(E_(mm - 1)); tst = tst * tst;
            if (tst <= (eps2 * fabsf(D_(mm))) * fabsf(D_(mm - 1)) + safmin) { m2 = mm; break; }
          }
        }
        if (m2 > lend) E_(m2 - 1) = 0.f;
        float p = D_(l);
        if (m2 == l) { D_(l) = p; l = l - 1; if (l >= lend) continue; break; }
        if (m2 == l - 1) {
          float rt1, rt2, cc, ss;
          slaev2f(D_(l - 1), E_(l - 1), D_(l), rt1, rt2, cc, ss);
          for (int i2 = 0; i2 < 3; ++i2) {
            float tmp = Z[i2][l - 1];
            Z[i2][l - 1] = cc * tmp - ss * Z[i2][l - 2];
            Z[i2][l - 2] = ss * tmp + cc * Z[i2][l - 2];
          }
          D_(l - 1) = rt1; D_(l) = rt2; E_(l - 1) = 0.f;
          l = l - 2; if (l >= lend) continue; break;
        }
        if (jtot == nmaxit) break;
        ++jtot;
        float g = (D_(l - 1) - p) / (2.f * E_(l - 1));
        float r = slapy2f(g, 1.f);
        float sgn_rg = (g >= 0.f) ? r : -r;
        g = D_(m2) - p + E_(l - 1) / (g + sgn_rg);
        float s = 1.f, c = 1.f;
        p = 0.f;
        float csv[2], ssv[2];
        for (int i2 = m2; i2 <= l - 1; ++i2) {
          float f = s * E_(i2);
          float b = c * E_(i2);
          slartgf(g, f, c, s, r);
          if (i2 != m2) E_(i2 - 1) = r;
          g = D_(i2) - p;
          r = (D_(i2 + 1) - g) * s + 2.f * c * b;
          p = s * r;
          D_(i2) = g + p;
          g = c * r - b;
          csv[i2 - m2] = c; ssv[i2 - m2] = s;
        }
        for (int j = m2; j <= l - 1; ++j) {
          float ct = csv[j - m2], st = ssv[j - m2];
          for (int i2 = 0; i2 < 3; ++i2) {
            float tmp = Z[i2][j];
            Z[i2][j]     = ct * tmp - st * Z[i2][j - 1];
            Z[i2][j - 1] = st * tmp + ct * Z[i2][j - 1];
          }
        }
        D_(l) = D_(l) - p;
        E_(l - 1) = g;
      }
    }
    if (iscale == 1) {
      float mul = anorm / ssfmax;
      for (int i2 = lsv; i2 <= lendsv; ++i2) D_(i2) *= mul;
      for (int i2 = lsv; i2 <= lendsv - 1; ++i2) E_(i2) *= mul;
    } else if (iscale == 2) {
      float mul = anorm / ssfmin;
      for (int i2 = lsv; i2 <= lendsv; ++i2) D_(i2) *= mul;
      for (int i2 = lsv; i2 <= lendsv - 1; ++i2) E_(i2) *= mul;
    }
  }
  for (int ii = 2; ii <= n; ++ii) {
    int i2 = ii - 1, k = i2;
    float p = D_(i2);
    for (int j = ii; j <= n; ++j) if (D_(j) < p) { k = j; p = D_(j); }
    if (k != i2) {
      D_(k) = D_(i2); D_(i2) = p;
      for (int rr = 0; rr < 3; ++rr) {
        float t = Z[rr][i2 - 1]; Z[rr][i2 - 1] = Z[rr][k - 1]; Z[rr][k - 1] = t;
      }
    }
  }
}

__device__ void eigh3_smallest(float a00, float a10, float a20, float a11, float a21, float a22,
                               float& nx, float& ny, float& nz) {
  float d[3], e[2];
  float Z[3][3] = {{1.f,0.f,0.f},{0.f,1.f,0.f},{0.f,0.f,1.f}};
  float tau, v2;
  {
    float alpha = a10, x = a20;
    float xnorm = fabsf(x);
    if (xnorm == 0.f) {
      tau = 0.f; v2 = 0.f;
      d[0] = a00; d[1] = a11; d[2] = a22;
      e[0] = alpha; e[1] = a21;
    } else {
      float beta = -copysignf(slapy2f(alpha, x), alpha);
      tau = (beta - alpha) / beta;
      v2 = x / (alpha - beta);
      float w0 = (tau * a11) + tau * (a21 * v2);
      float w1 = (tau * a21) + (tau * v2) * a22;
      float ac = (-0.5f * tau) * (w0 + w1 * v2);
      w0 = w0 + ac;
      w1 = w1 + ac * v2;
      d[0] = a00;
      d[1] = (a11 - w0) - w0;
      d[2] = (a22 - v2 * w1) - w1 * v2;
      e[0] = beta;
      e[1] = (a21 - v2 * w0) - w1;
    }
  }
  ssteqr3(d, e, Z);
  if (tau != 0.f) {
    for (int c = 0; c < 3; ++c) {
      float w = Z[1][c] + Z[2][c] * v2;
      float temp = (-tau) * w;
      Z[1][c] = Z[1][c] + temp;
      Z[2][c] = Z[2][c] + v2 * temp;
    }
  }
  nx = Z[0][0]; ny = Z[1][0]; nz = Z[2][0];
}

// ---------------- K0: init workspace ----------------
__global__ void k0_init(unsigned long long* cand, int* sample_idx) {
  int t = blockIdx.x * blockDim.x + threadIdx.x;
  if (t < 2 * POOL) cand[t] = 0ull;
  if (t == 0) sample_idx[0] = 0;
}

// ---------------- K1: batched FPS ----------------
// Round-3 post-mortem: 32-entry/lane register pool spilled (VGPR capped at
// 188 + scratch traffic, WRITE_SIZE +256KB) and the AoS act4 handoff was a
// 64-way LDS bank conflict (1.05e7 cycles). r1's 16/lane SoA shape (VGPR
// 120, zero conflicts) is the proven no-spill envelope. So: SHRINK THE POOL
// TO THE ENVELOPE. POOL=1024 (M_WAVE=4) => full pool = 16 entries/lane in
// wave0 registers. No T2, no refill path, no event loop; one barrier pair
// per batch. Handoff is SoA word-indexed (act_x[j*256+tidx]): write bank =
// tidx%32, read bank = lane%32 -- both conflict-free.
// Exactness: pool = each wave's lex-top-4; any unpublished point <=lex its
// wave's 4th-best <=lex Tmd (max of 4th-bests); pool entries min-updated
// exactly vs every in-batch pick (winner self-kills via d2=0); pick while
// winner >=lex Tmd. Winner >lex Tmd-thread's own 4th-best => >=1 pick/batch
// (no livelock). Ties via idf = 0x3FFFFF - index (larger idf == smaller
// original index == reference argmax-first semantics).
__global__ __launch_bounds__(FPS_THREADS, 1) void k1_fps(
    const float* __restrict__ pos,
    unsigned long long* __restrict__ cand,
    int* __restrict__ sample_idx) {
  __shared__ float4 sel4[SEL_CAP];
  __shared__ float act_x[POOL], act_y[POOL], act_z[POOL], act_md[POOL];
  __shared__ unsigned act_idf[POOL];
  __shared__ float thrT_md[FPS_THREADS];     // per-thread 4th-best (Tmd source)
  __shared__ unsigned thrT_idf[FPS_THREADS];
  __shared__ int sh_pc;

  const int tidx = threadIdx.x;
  const int lane = tidx & 63;
  const int gtid = blockIdx.x * FPS_THREADS + tidx;

  float px[FPS_PPT], py[FPS_PPT], pz[FPS_PPT], md[FPS_PPT];
#pragma unroll
  for (int k = 0; k < FPS_PPT; ++k) {
    int p = gtid + k * (FPS_BLOCKS * FPS_THREADS);
    px[k] = pos[3 * p]; py[k] = pos[3 * p + 1]; pz[k] = pos[3 * p + 2];
    md[k] = 1e10f;
  }
  const unsigned idf0 = 0x3FFFFFu - (unsigned)gtid;
  if (tidx == 0) sel4[0] = make_float4(pos[0], pos[1], pos[2], 0.f);
  __syncthreads();
  int sel_cnt = 1, total = 0, bt = 0;
  while (total < NUM_SAMPLE - 1) {
    ++bt;
    // ---- Phase A: owner md updates vs previous batch's picks (pipelined) ----
    {
      float4 sc = sel4[0];
      for (int s = 0; s < sel_cnt; ++s) {
        float4 sn = (s + 1 < sel_cnt) ? sel4[s + 1] : sc;
#pragma unroll
        for (int k = 0; k < FPS_PPT; ++k)
          md[k] = fminf(md[k], d2rn(px[k], py[k], pz[k], sc.x, sc.y, sc.z));
        sc = sn;
      }
    }
    // ---- per-wave top-4 via DPP (registers only, barrier-free) ----
    const unsigned tag = (unsigned)bt & 1023u;
    unsigned long long* setbase = cand + (size_t)(bt & 1) * POOL;
    {
      float wmd[FPS_PPT];
#pragma unroll
      for (int k = 0; k < FPS_PPT; ++k) wmd[k] = md[k];
      unsigned long long mypub = 0ull;
      for (int r = 0; r < M_WAVE; ++r) {
        float bm = wmd[0]; unsigned bidf = idf0;
#pragma unroll
        for (int k = 1; k < FPS_PPT; ++k) {
          unsigned idfk = idf0 - ((unsigned)k << 14);
          if (wmd[k] > bm || (wmd[k] == bm && idfk > bidf)) { bm = wmd[k]; bidf = idfk; }
        }
        float wmx = wave_fmax_bcast(bm);
        unsigned tb = (bm == wmx) ? bidf : 0u;
        unsigned widf = wave_umax_bcast(tb);
        if (lane == r)
          mypub = ((unsigned long long)__float_as_uint(wmx) << 32) |
                  ((unsigned long long)widf << 10);
#pragma unroll
        for (int k = 0; k < FPS_PPT; ++k) {
          unsigned idfk = idf0 - ((unsigned)k << 14);
          if (wmd[k] == wmx && idfk == widf) wmd[k] = -1.f;
        }
      }
      if (lane < M_WAVE)
        __hip_atomic_store(setbase + blockIdx.x * (4 * M_WAVE) + (tidx >> 6) * M_WAVE + lane,
                           mypub | tag, __ATOMIC_RELAXED, __HIP_MEMORY_SCOPE_AGENT);
    }
    // ---- Phase B: poll own 4 words; gather xyz inline as tags arrive ----
    const int base_w = tidx * ENT_PER_T;
    {
      float cmd[ENT_PER_T]; unsigned cidf[ENT_PER_T];
      float cx[ENT_PER_T], cy[ENT_PER_T], cz[ENT_PER_T];
      unsigned done = 0;
      while (done != 0xFu) {
#pragma unroll
        for (int j = 0; j < ENT_PER_T; ++j) {
          if (!((done >> j) & 1u)) {
            unsigned long long v = __hip_atomic_load(setbase + base_w + j,
                                                     __ATOMIC_RELAXED, __HIP_MEMORY_SCOPE_AGENT);
            if ((unsigned)(v & 1023ull) == tag) {
              done |= 1u << j;
              cmd[j] = __uint_as_float((unsigned)(v >> 32));
              cidf[j] = (unsigned)((v >> 10) & 0x3FFFFFull);
              int gidx = 0x3FFFFF - (int)cidf[j];
              cx[j] = pos[3 * gidx]; cy[j] = pos[3 * gidx + 1]; cz[j] = pos[3 * gidx + 2];
            }
          }
        }
        if (done != 0xFu) __builtin_amdgcn_s_sleep(1);
      }
      // ---- handoff: SoA word-indexed (conflict-free both sides) ----
#pragma unroll
      for (int j = 0; j < ENT_PER_T; ++j) {
        int e = j * FPS_THREADS + tidx;
        act_x[e] = cx[j]; act_y[e] = cy[j]; act_z[e] = cz[j];
        act_md[e] = cmd[j]; act_idf[e] = cidf[j];
      }
      thrT_md[tidx] = cmd[ENT_PER_T - 1]; thrT_idf[tidx] = cidf[ENT_PER_T - 1];
    }
    __syncthreads();
    const int room = (NUM_SAMPLE - 1) - total;
    // ---- wave0: register-resident FULL pool, pick to batch end, no refills ----
    if (tidx < 64) {
      float q_md[QD], q_x[QD], q_y[QD], q_z[QD];
      unsigned q_idf[QD];
#pragma unroll
      for (int r = 0; r < QD; ++r) {
        int e2 = lane + 64 * r;
        q_x[r] = act_x[e2]; q_y[r] = act_y[e2]; q_z[r] = act_z[e2];
        q_md[r] = act_md[e2]; q_idf[r] = act_idf[e2];
      }
      // Tmd = lex-max over 256 pool-waves of their 4th-best
      float rm = thrT_md[lane]; unsigned ri = thrT_idf[lane];
#pragma unroll
      for (int r = 1; r < 4; ++r) {
        float m = thrT_md[lane + 64 * r]; unsigned ii = thrT_idf[lane + 64 * r];
        if (lex_gt(m, ii, rm, ri)) { rm = m; ri = ii; }
      }
      float Tmd = wave_fmax_bcast(rm);
      unsigned tbT = (rm == Tmd) ? ri : 0u;
      unsigned Tidf = wave_umax_bcast(tbT);

      int picks = 0;
      float X = 1e30f, Y = 1e30f, Z = 1e30f;   // priming: d2 -> inf, fmin no-op
      for (;;) {
        // fused: apply last pick's suppression + local lex-argmax
        float bm = -1.f; unsigned bidf = 0u;
        float bx = 0.f, by = 0.f, bz = 0.f;
#pragma unroll
        for (int j = 0; j < QD; ++j) {
          float nd = fminf(q_md[j], d2rn(q_x[j], q_y[j], q_z[j], X, Y, Z));
          q_md[j] = nd;
          if (lex_gt(nd, q_idf[j], bm, bidf)) {
            bm = nd; bidf = q_idf[j]; bx = q_x[j]; by = q_y[j]; bz = q_z[j];
          }
        }
        float wmx = wave_fmax_bcast(bm);
        unsigned long long ball = __ballot(bm == wmx);
        unsigned widf; int owner;
        if (__builtin_popcountll(ball) == 1) {
          owner = __builtin_ctzll(ball);
          widf = (unsigned)__builtin_amdgcn_readlane((int)bidf, owner);
        } else {  // md tie across lanes: rare exact-tiebreak path
          unsigned tb = (bm == wmx) ? bidf : 0u;
          widf = wave_umax_bcast(tb);
          owner = __builtin_ctzll(__ballot(bm == wmx && bidf == widf));
        }
        if (picks >= room) break;
        if (!lex_ge(wmx, widf, Tmd, Tidf)) break;   // batch done
        X = __int_as_float(__builtin_amdgcn_readlane(__float_as_int(bx), owner));
        Y = __int_as_float(__builtin_amdgcn_readlane(__float_as_int(by), owner));
        Z = __int_as_float(__builtin_amdgcn_readlane(__float_as_int(bz), owner));
        if (lane == 0) {
          sel4[picks] = make_float4(X, Y, Z, 0.f);
          if (blockIdx.x == 0) sample_idx[1 + total + picks] = 0x3FFFFF - (int)widf;
        }
        ++picks;
      }
      if (lane == 0) sh_pc = picks;
    }
    __syncthreads();
    sel_cnt = sh_pc;
    total += sel_cnt;
  }
}

// ---------------- K2a: wave-per-sample KNN + covariance + eigh -> feats9 ----------------
__global__ __launch_bounds__(256) void k2a_knn(
    const float* __restrict__ pos, const float* __restrict__ col,
    const int* __restrict__ sample_idx,
    float4* __restrict__ sp4g, float* __restrict__ feats9) {
  __shared__ float4 sp[NUM_SAMPLE];
  const int tid = threadIdx.x, lane = tid & 63, wv = tid >> 6;
  for (int i = tid; i < NUM_SAMPLE; i += 256) {
    int idx = sample_idx[i];
    float x = pos[3 * idx], y = pos[3 * idx + 1], z = pos[3 * idx + 2];
    float nrm = addrn(addrn(mulrn(x, x), mulrn(y, y)), mulrn(z, z));
    float4 v = make_float4(x, y, z, nrm);
    sp[i] = v;
    if (blockIdx.x == 0) sp4g[i] = v;
  }
  __syncthreads();
  for (int it = 0; it < 4; ++it) {
    const int r = blockIdx.x * 16 + wv * 4 + it;
    float4 pr = sp[r];
    unsigned long long kk[16];
#pragma unroll
    for (int k = 0; k < 16; ++k) {
      int j = lane + 64 * k;
      float4 q = sp[j];
      float dot = fmaf(pr.z, q.z, fmaf(pr.y, q.y, mulrn(pr.x, q.x)));
      float d2 = subrn(addrn(pr.w, q.w), mulrn(2.f, dot));
      unsigned b = __float_as_uint(d2);
      unsigned sbits = (b & 0x80000000u) ? ~b : (b | 0x80000000u);
      kk[k] = ((unsigned long long)sbits << 32) | (unsigned)j;
    }
    int bi[17];
#pragma unroll
    for (int rsel = 0; rsel < 17; ++rsel) {
      unsigned long long best = 0xFFFFFFFFFFFFFFFFull;
#pragma unroll
      for (int k = 0; k < 16; ++k) best = (kk[k] < best) ? kk[k] : best;
#pragma unroll
      for (int mk = 1; mk < 64; mk <<= 1) {
        unsigned long long o = (unsigned long long)__shfl_xor((long long)best, mk, 64);
        best = (o < best) ? o : best;
      }
      int j = (int)(best & 0xFFFFFFFFull);
      bi[rsel] = j;
#pragma unroll
      for (int k = 0; k < 16; ++k)
        if (((j >> 6) == k) && ((j & 63) == lane)) kk[k] = 0xFFFFFFFFFFFFFFFFull;
    }
    float mx = 0.f, my = 0.f, mz = 0.f;
#pragma unroll
    for (int k = 1; k <= 16; ++k) {
      float4 q = sp[bi[k]];
      mx = addrn(mx, q.x); my = addrn(my, q.y); mz = addrn(mz, q.z);
    }
    mx = mulrn(mx, 0.0625f); my = mulrn(my, 0.0625f); mz = mulrn(mz, 0.0625f);
    float c00 = 0.f, c01 = 0.f, c02 = 0.f, c11 = 0.f, c12 = 0.f, c22 = 0.f;
#pragma unroll
    for (int k = 1; k <= 16; ++k) {
      float4 q = sp[bi[k]];
      float dx = subrn(q.x, mx), dy = subrn(q.y, my), dz = subrn(q.z, mz);
      c00 = addrn(c00, mulrn(dx, dx)); c01 = addrn(c01, mulrn(dx, dy));
      c02 = addrn(c02, mulrn(dx, dz)); c11 = addrn(c11, mulrn(dy, dy));
      c12 = addrn(c12, mulrn(dy, dz)); c22 = addrn(c22, mulrn(dz, dz));
    }
    c00 /= 15.f; c01 /= 15.f; c02 /= 15.f; c11 /= 15.f; c12 /= 15.f; c22 /= 15.f;

    float n0, n1, n2;
    eigh3_smallest(c00, c01, c02, c11, c12, c22, n0, n1, n2);
    float nn = __fsqrt_rn(addrn(addrn(mulrn(n0, n0), mulrn(n1, n1)), mulrn(n2, n2)));
    float den = addrn(nn, 1e-8f);
    n0 /= den; n1 /= den; n2 /= den;

    if (lane == 0) {
      int myidx = sample_idx[r];
      float* f = feats9 + r * 9;
      f[0] = pr.x; f[1] = pr.y; f[2] = pr.z;
      f[3] = col[3 * myidx]; f[4] = col[3 * myidx + 1]; f[5] = col[3 * myidx + 2];
      f[6] = n0; f[7] = n1; f[8] = n2;
    }
  }
}

// ---------------- K2b: per-thread MLP (order identical to passing version) ----------------
__global__ __launch_bounds__(64) void k2b_mlp(
    const float* __restrict__ W1, const float* __restrict__ b1,
    const float* __restrict__ W2, const float* __restrict__ b2,
    const float* __restrict__ W3, const float* __restrict__ b3,
    const float* __restrict__ feats9,
    float* __restrict__ featd, int* __restrict__ lbl) {
  __shared__ float hbuf[64][129];
  const int tid = threadIdx.x;
  const int r = blockIdx.x * 64 + tid;
  float f9[9];
#pragma unroll
  for (int k = 0; k < 9; ++k) f9[k] = feats9[r * 9 + k];
  for (int jo = 0; jo < 128; ++jo) {
    float acc = 0.f;
#pragma unroll
    for (int k = 0; k < 9; ++k) acc = fmaf(f9[k], W1[k * 128 + jo], acc);
    acc += b1[jo];
    hbuf[tid][jo] = fmaxf(acc, 0.f);
  }
  float pd[13];
#pragma unroll
  for (int c = 0; c < 13; ++c) pd[c] = 0.f;
  for (int io = 0; io < 128; io += 16) {
    float acc[16];
#pragma unroll
    for (int t = 0; t < 16; ++t) acc[t] = 0.f;
    for (int j = 0; j < 128; ++j) {
      float hj = hbuf[tid][j];
#pragma unroll
      for (int t = 0; t < 16; ++t) acc[t] = fmaf(hj, W2[j * 128 + io + t], acc[t]);
    }
#pragma unroll
    for (int t = 0; t < 16; ++t) {
      float h2 = fmaxf(acc[t] + b2[io + t], 0.f);
#pragma unroll
      for (int c = 0; c < 13; ++c) pd[c] = fmaf(h2, W3[(io + t) * 13 + c], pd[c]);
    }
  }
#pragma unroll
  for (int c = 0; c < 13; ++c) pd[c] += b3[c];
  float mmax = pd[0];
#pragma unroll
  for (int c = 1; c < 13; ++c) mmax = fmaxf(mmax, pd[c]);
  float es = 0.f, ev[13];
#pragma unroll
  for (int c = 0; c < 13; ++c) { ev[c] = expf(pd[c] - mmax); es += ev[c]; }
#pragma unroll
  for (int c = 0; c < 13; ++c) featd[r * 13 + c] = ev[c] / es;
  int am = 0; float bv = pd[0];
#pragma unroll
  for (int c = 1; c < 13; ++c) { if (pd[c] > bv) { bv = pd[c]; am = c; } }
  lbl[r] = am;
}

// ---------------- K3: nearest sample + gather outputs ----------------
__global__ __launch_bounds__(256) void k3_assign(
    const float* __restrict__ pos,
    const float4* __restrict__ sp4g,
    const float* __restrict__ featd,
    const int* __restrict__ lbl,
    float* __restrict__ out) {
  __shared__ float4 sp[NUM_SAMPLE];
  for (int i = threadIdx.x; i < NUM_SAMPLE; i += 256) sp[i] = sp4g[i];
  __syncthreads();
  int i = blockIdx.x * 256 + threadIdx.x;
  float x = pos[3 * i], y = pos[3 * i + 1], z = pos[3 * i + 2];
  float an = addrn(addrn(mulrn(x, x), mulrn(y, y)), mulrn(z, z));
  float bestd = 3.402823466e+38f; int bestj = 0;
#pragma unroll 4
  for (int j = 0; j < NUM_SAMPLE; ++j) {
    float4 q = sp[j];
    float dot = fmaf(z, q.z, fmaf(y, q.y, mulrn(x, q.x)));
    float d2 = subrn(addrn(an, q.w), mulrn(2.f, dot));
    if (d2 < bestd) { bestd = d2; bestj = j; }
  }
  const float* fr = featd + bestj * 13;
  float* o = out + (size_t)i * 13;
#pragma unroll
  for (int c = 0; c < 13; ++c) o[c] = fr[c];
  out[(size_t)N_TOTAL * 13 + i] = (float)lbl[bestj];
}

extern "C" void kernel_launch(void* const* d_in, const int* in_sizes, int n_in,
                              void* d_out, int out_size, void* d_ws, size_t ws_size,
                              hipStream_t stream) {
  (void)in_sizes; (void)n_in; (void)out_size; (void)ws_size;
  const float* pos = (const float*)d_in[0];
  const float* col = (const float*)d_in[1];
  const float* W1 = (const float*)d_in[2];
  const float* b1 = (const float*)d_in[3];
  const float* W2 = (const float*)d_in[4];
  const float* b2 = (const float*)d_in[5];
  const float* W3 = (const float*)d_in[6];
  const float* b3 = (const float*)d_in[7];
  float* out = (float*)d_out;

  char* w = (char*)d_ws;
  unsigned long long* cand = (unsigned long long*)(w);           // 16 KiB (2 sets x 1024)
  int* sample_idx = (int*)(w + 65536);                           //  4 KiB
  float4* sp4g = (float4*)(w + 73728);                           // 16 KiB
  float* featd = (float*)(w + 90112);                            // 52 KiB
  int* lbl = (int*)(w + 143360);                                 //  4 KiB
  float* feats9 = (float*)(w + 147456);                          // 36 KiB

  k0_init<<<16, 256, 0, stream>>>(cand, sample_idx);
  k1_fps<<<FPS_BLOCKS, FPS_THREADS, 0, stream>>>(pos, cand, sample_idx);
  k2a_knn<<<64, 256, 0, stream>>>(pos, col, sample_idx, sp4g, feats9);
  k2b_mlp<<<16, 64, 0, stream>>>(W1, b1, W2, b2, W3, b3, feats9, featd, lbl);
  k3_assign<<<N_TOTAL / 256, 256, 0, stream>>>(pos, sp4g, featd, lbl, out);
}